// Round 1
// 1730.026 us; speedup vs baseline: 1.0833x; 1.0833x over previous
//
#include <hip/hip_runtime.h>
#include <math.h>

typedef unsigned short u16;
typedef unsigned int u32;
typedef unsigned long long u64;
typedef __attribute__((ext_vector_type(4))) float f32x4;
typedef __attribute__((ext_vector_type(8))) __bf16 bf16x8;

#define SEQ 2048
#define N1 21504      // 3*HID + MLP
#define K1 3072       // HID
#define CATK 15360    // HID + MLP

__device__ __forceinline__ u16 f2bf(float f){
  u32 u = __float_as_uint(f);
  u32 r = u + 0x7FFFu + ((u >> 16) & 1u);
  return (u16)(r >> 16);
}
__device__ __forceinline__ float bf2f(u16 h){
  return __uint_as_float(((u32)h) << 16);
}
__device__ __forceinline__ void gl_lds16(const void* g, void* l){
  __builtin_amdgcn_global_load_lds(
      (const __attribute__((address_space(1))) void*)(size_t)g,
      (__attribute__((address_space(3))) void*)(u32)(size_t)l, 16, 0, 0);
}
__device__ __forceinline__ f32x4 zero4(){ f32x4 z; z[0]=0.f; z[1]=0.f; z[2]=0.f; z[3]=0.f; return z; }

// ---------------- weight prep kernels ----------------
// cast w1 rows [9216,21504) (the MLP part, no lora) to bf16
__global__ void __launch_bounds__(256) cast_w1_tail(
    const float* __restrict__ w1, u16* __restrict__ out)
{
  int gid = blockIdx.x*256 + threadIdx.x;     // 12288*384
  int n = 9216 + gid / 384;
  int k8 = (gid - (n-9216)*384) * 8;
  const float* src = &w1[(size_t)n*K1 + k8];
  union { u16 u[8]; uint4 q; } t;
  #pragma unroll
  for (int j=0;j<8;j++) t.u[j] = f2bf(src[j]);
  *(uint4*)&out[(size_t)n*K1 + k8] = t.q;
}

// U (9216 x 128 bf16): rows n in block b=n/3072 hold up_b[n%3072][:] in cols [32b,32b+32)
__global__ void __launch_bounds__(256) build_ustack(
    const float* __restrict__ lqu, const float* __restrict__ lku,
    const float* __restrict__ lvu, u16* __restrict__ out)
{
  int gid = blockIdx.x*256 + threadIdx.x;     // 9216*16
  int n = gid >> 4;
  int k8 = (gid & 15) * 8;
  int b = n / 3072;
  const float* up = (b==0)? lqu : (b==1)? lku : lvu;
  int nl = n - b*3072;
  union { u16 u[8]; uint4 q; } t;
  #pragma unroll
  for (int j=0;j<8;j++){
    int r = k8 + j - 32*b;
    t.u[j] = (r >= 0 && r < 32) ? f2bf(up[(size_t)nl*32 + r]) : (u16)0;
  }
  *(uint4*)&out[(size_t)n*128 + k8] = t.q;
}

// DT (3072 x 128 bf16): DT[k][r] = down_{r/32}[r%32][k], zero for r>=96
__global__ void __launch_bounds__(256) build_dcatT(
    const float* __restrict__ lqd, const float* __restrict__ lkd,
    const float* __restrict__ lvd, u16* __restrict__ out)
{
  int gid = blockIdx.x*256 + threadIdx.x;     // 3072*16
  int k = gid >> 4;
  int r8 = (gid & 15) * 8;
  union { u16 u[8]; uint4 q; } t;
  #pragma unroll
  for (int j=0;j<8;j++){
    int r = r8 + j;
    float v = (r < 32) ? lqd[(size_t)r*3072 + k]
            : (r < 64) ? lkd[(size_t)(r-32)*3072 + k]
            : (r < 96) ? lvd[(size_t)(r-64)*3072 + k] : 0.f;
    t.u[j] = f2bf(v);
  }
  *(uint4*)&out[(size_t)k*128 + r8] = t.q;
}

// pu (3072 x 64) -> bf16 cast
__global__ void __launch_bounds__(256) build_pubf(
    const float* __restrict__ pu, u16* __restrict__ out)
{
  int gid = blockIdx.x*256 + threadIdx.x;     // 3072*8
  int n = gid >> 3;
  int r8 = (gid & 7) * 8;
  union { u16 u[8]; uint4 q; } t;
  #pragma unroll
  for (int j=0;j<8;j++) t.u[j] = f2bf(pu[(size_t)n*64 + r8 + j]);
  *(uint4*)&out[(size_t)n*64 + r8] = t.q;
}

// pdT (15360 x 64 bf16): pdT[j][r] = pd[r][j]
__global__ void __launch_bounds__(256) build_pdT(
    const float* __restrict__ pd, u16* __restrict__ out)
{
  int gid = blockIdx.x*256 + threadIdx.x;     // 15360*8
  int jj = gid >> 3;
  int r8 = (gid & 7) * 8;
  union { u16 u[8]; uint4 q; } t;
  #pragma unroll
  for (int j=0;j<8;j++) t.u[j] = f2bf(pd[(size_t)(r8+j)*15360 + jj]);
  *(uint4*)&out[(size_t)jj*64 + r8] = t.q;
}

// ---------------- small vector kernels ----------------
__global__ void __launch_bounds__(256) silu_kernel(const float* __restrict__ v, float* __restrict__ sv){
  int i = blockIdx.x*256 + threadIdx.x;
  float x = v[i];
  sv[i] = x / (1.f + __expf(-x));
}

__global__ void __launch_bounds__(256) modgemv_kernel(
    const float* __restrict__ sv, const float* __restrict__ mw,
    const float* __restrict__ mb, float* __restrict__ mout)
{
  int n = blockIdx.x, tid = threadIdx.x;
  const float* wr = mw + (size_t)n*3072;
  float p = 0.f;
  for (int c = tid; c < 3072; c += 256) p += sv[c]*wr[c];
  #pragma unroll
  for (int o=32;o>0;o>>=1) p += __shfl_down(p,o,64);
  __shared__ float red[4];
  if ((tid & 63)==0) red[tid>>6] = p;
  __syncthreads();
  if (tid==0) mout[n] = red[0]+red[1]+red[2]+red[3] + mb[n];
}

__global__ void __launch_bounds__(256) xmod_kernel(
    const float* __restrict__ x, const float* __restrict__ m, u16* __restrict__ xm)
{
  int l = blockIdx.x, tid = threadIdx.x;
  const float* xr = x + (size_t)l*3072;
  float s1=0.f, s2=0.f;
  for (int c=tid;c<3072;c+=256){ float v = xr[c]; s1+=v; s2+=v*v; }
  #pragma unroll
  for (int o=32;o>0;o>>=1){ s1 += __shfl_down(s1,o,64); s2 += __shfl_down(s2,o,64); }
  __shared__ float r1[4], r2[4];
  if ((tid&63)==0){ r1[tid>>6]=s1; r2[tid>>6]=s2; }
  __syncthreads();
  float su = r1[0]+r1[1]+r1[2]+r1[3];
  float sq = r2[0]+r2[1]+r2[2]+r2[3];
  float mu = su / 3072.f;
  float var = sq/3072.f - mu*mu;
  float rstd = rsqrtf(var + 1e-6f);
  u16* orow = xm + (size_t)l*K1;
  for (int c=tid;c<3072;c+=256){
    float v = (xr[c]-mu)*rstd;
    v = v*(1.f + m[3072+c]) + m[c];
    orow[c] = f2bf(v);
  }
}

__global__ void __launch_bounds__(256) gelu_kernel(const u16* __restrict__ h, u16* __restrict__ cat){
  int j = blockIdx.x*256 + threadIdx.x;  // < 12288
  int l = blockIdx.y;
  float v = bf2f(h[(size_t)l*N1 + 9216 + j]);
  float u = 0.7978845608028654f * (v + 0.044715f*v*v*v);
  float t = 1.f - 2.f/(__expf(2.f*u) + 1.f);   // tanh(u)
  cat[(size_t)l*CATK + 3072 + j] = f2bf(0.5f*v*(1.f + t));
}

__global__ void __launch_bounds__(128) qkv_kernel(
    const u16* __restrict__ h, const float* __restrict__ pe,
    const float* __restrict__ qs, const float* __restrict__ ks,
    u16* __restrict__ qbf, u16* __restrict__ kbf)
{
  const int l = blockIdx.x, hh = blockIdx.y, d = threadIdx.x;
  __shared__ float lq[128], lk[128];
  __shared__ float red[4];
  size_t base = (size_t)l*N1 + (size_t)hh*128 + d;
  float qv = bf2f(h[base]);
  float kv = bf2f(h[base + 3072]);
  float pq = qv*qv, pk = kv*kv;
  #pragma unroll
  for (int o=32;o>0;o>>=1){ pq += __shfl_down(pq,o,64); pk += __shfl_down(pk,o,64); }
  if ((d & 63)==0){ red[(d>>6)*2] = pq; red[(d>>6)*2+1] = pk; }
  __syncthreads();
  float rq = rsqrtf((red[0]+red[2])/128.f + 1e-6f);
  float rk = rsqrtf((red[1]+red[3])/128.f + 1e-6f);
  lq[d] = qv*rq*qs[d];
  lk[d] = kv*rk*ks[d];
  __syncthreads();
  int i = d >> 1;
  const float* peb = pe + ((size_t)l*64 + i)*4 + (size_t)(d&1)*2;
  float qo = peb[0]*lq[2*i] + peb[1]*lq[2*i+1];
  float ko = peb[0]*lk[2*i] + peb[1]*lk[2*i+1];
  size_t ob = ((size_t)hh*SEQ + l)*128 + d;
  qbf[ob] = f2bf(qo);
  kbf[ob] = f2bf(ko);
}

// ---------------- GEMM: C[m,n] = sum_k A[m,k]*B[n,k] (+epilogue) ----------------
// MODE 0: bf16 store, +bias
// MODE 1: f32 store, x + gate*(acc+bias)
// MODE 3: bf16 store of (acc + addin_f32[row*ldadd+col])   (weight-fold epilogue)
template<int MODE>
__global__ void __launch_bounds__(256) gemm_bt(
    const u16* __restrict__ A, const u16* __restrict__ B, void* __restrict__ C,
    int K, int lda, int ldb, int ldc, int ldadd,
    const float* __restrict__ bias, const float* __restrict__ xres,
    const float* __restrict__ gate)
{
  __shared__ u16 sA[128*64];
  __shared__ u16 sB[128*64];
  const int tid = threadIdx.x;
  const int lane = tid & 63;
  const int wv = tid >> 6;
  const int quad = lane >> 4;
  const int l16 = lane & 15;
  const int rw = (wv >> 1) * 64;
  const int cw = (wv & 1) * 64;
  const int m0 = blockIdx.x * 128;   // m fastest for B-tile L2 reuse
  const int n0 = blockIdx.y * 128;

  f32x4 acc[4][4];
  #pragma unroll
  for (int i=0;i<4;i++){
    #pragma unroll
    for (int j=0;j<4;j++) acc[i][j] = zero4();
  }

  for (int kb = 0; kb < K; kb += 64){
    #pragma unroll
    for (int i=0;i<4;i++){
      int c = i*256 + tid, r = c >> 3, s = c & 7, g = s ^ (r & 7);
      gl_lds16(A + (size_t)(m0 + r)*lda + kb + g*8, &sA[c*8]);
    }
    #pragma unroll
    for (int i=0;i<4;i++){
      int c = i*256 + tid, r = c >> 3, s = c & 7, g = s ^ (r & 7);
      gl_lds16(B + (size_t)(n0 + r)*ldb + kb + g*8, &sB[c*8]);
    }
    __syncthreads();
    #pragma unroll
    for (int kc=0; kc<2; kc++){
      bf16x8 af[4], bfr[4];
      #pragma unroll
      for (int mt=0; mt<4; mt++){
        int row = rw + mt*16 + l16;
        int s = (kc*4 + quad) ^ (row & 7);
        af[mt] = *(const bf16x8*)&sA[row*64 + s*8];
      }
      #pragma unroll
      for (int nt=0; nt<4; nt++){
        int row = cw + nt*16 + l16;
        int s = (kc*4 + quad) ^ (row & 7);
        bfr[nt] = *(const bf16x8*)&sB[row*64 + s*8];
      }
      #pragma unroll
      for (int mt=0; mt<4; mt++){
        #pragma unroll
        for (int nt=0; nt<4; nt++)
          acc[mt][nt] = __builtin_amdgcn_mfma_f32_16x16x32_bf16(af[mt], bfr[nt], acc[mt][nt], 0, 0, 0);
      }
    }
    __syncthreads();
  }

  #pragma unroll
  for (int mt=0; mt<4; mt++){
    #pragma unroll
    for (int nt=0; nt<4; nt++){
      #pragma unroll
      for (int r=0;r<4;r++){
        int row = m0 + rw + mt*16 + quad*4 + r;
        int col = n0 + cw + nt*16 + l16;
        float v = acc[mt][nt][r];
        if (MODE==0){
          v += bias[col];
          ((u16*)C)[(size_t)row*ldc + col] = f2bf(v);
        } else if (MODE==1){
          v += bias[col];
          ((float*)C)[(size_t)row*ldc + col] = xres[(size_t)row*3072 + col] + gate[col]*v;
        } else {
          v += xres[(size_t)row*ldadd + col];
          ((u16*)C)[(size_t)row*ldc + col] = f2bf(v);
        }
      }
    }
  }
}

// ---------------- 256x256 8-phase pipelined GEMM (T2+T3+T4+T5) ----------------
// C[m,n] = sum_k A[m,k]*B[n,k] + bias[n], bf16 out. K % 64 == 0, M % 256 == 0, N % 256 == 0.
// 8 waves (2M x 4N), per-wave C = 128x64. BK=64, LDS double-buffered (128 KiB).
// Per K-tile: 4 phases, quadrant order (qm,qn) = (0,0),(0,1),(1,0),(1,1).
// Prefetch schedule (counted vmcnt, never 0 in steady state):
//   ph0: stage A-Q13(t+1)   ph1: stage B-S1(t+1)
//   ph2: stage A-Q02(t+2)   ph3: stage B-S0(t+2)
//   vmcnt(6) end of ph0, vmcnt(8) end of ph3 (exact; see derivation in session notes)

#define CFENCE asm volatile("" ::: "memory")
#define VMCNT(n) asm volatile("s_waitcnt vmcnt(" #n ")" ::: "memory")

// stage 64 contiguous rows [rb, rb+64) of a 256x64 tile: 512 threads x 16B
__device__ __forceinline__ void stA64(const u16* __restrict__ g, u16* __restrict__ lds,
                                      int rb, int kb, int lda, int tid){
  int ri = tid >> 3, s = tid & 7;
  int R = rb + ri;                    // rb % 8 == 0 -> R&7 == ri&7
  gl_lds16(g + (size_t)R*lda + kb + ((s ^ (R & 7)) << 3), &lds[(R << 6) + (s << 3)]);
}
// stage two 32-row stripes [rb,rb+32) and [rb+64,rb+96): 512 threads x 16B
__device__ __forceinline__ void stB32x2(const u16* __restrict__ g, u16* __restrict__ lds,
                                        int rb, int kb, int ldb, int tid){
  int ri = tid >> 3, s = tid & 7;
  int R = rb + (ri & 31) + ((ri >> 5) << 6);
  gl_lds16(g + (size_t)R*ldb + kb + ((s ^ (R & 7)) << 3), &lds[(R << 6) + (s << 3)]);
}

__global__ void __launch_bounds__(512, 2) gemm256_bias(
    const u16* __restrict__ A, const u16* __restrict__ B, u16* __restrict__ C,
    int K, int lda, int ldb, int ldc, const float* __restrict__ bias)
{
  __shared__ u16 sA[2][256*64];
  __shared__ u16 sB[2][256*64];
  const int tid  = threadIdx.x;
  const int lane = tid & 63;
  const int wv   = tid >> 6;
  const int quad = lane >> 4;
  const int l16  = lane & 15;
  const int wm   = wv >> 2;          // 0..1
  const int wn   = wv & 3;           // 0..3
  const int m0   = blockIdx.x * 256;
  const int n0   = blockIdx.y * 256;
  const u16* Ab  = A + (size_t)m0 * lda;
  const u16* Bb  = B + (size_t)n0 * ldb;
  const int NT   = K >> 6;

  f32x4 acc[8][4];
  #pragma unroll
  for (int i=0;i<8;i++){
    #pragma unroll
    for (int j=0;j<4;j++) acc[i][j] = zero4();
  }

  // prologue: AQ02(0) BS0(0) AQ13(0) BS1(0) AQ02(1) BS0(1)  (12 loads/wave max)
  stA64 (Ab, sA[0],   0, 0, lda, tid);  stA64 (Ab, sA[0], 128, 0, lda, tid);
  stB32x2(Bb, sB[0],  0, 0, ldb, tid);  stB32x2(Bb, sB[0], 128, 0, ldb, tid);
  stA64 (Ab, sA[0],  64, 0, lda, tid);  stA64 (Ab, sA[0], 192, 0, lda, tid);
  stB32x2(Bb, sB[0], 32, 0, ldb, tid);  stB32x2(Bb, sB[0], 160, 0, ldb, tid);
  if (NT > 1){
    stA64 (Ab, sA[1],   0, 64, lda, tid);  stA64 (Ab, sA[1], 128, 64, lda, tid);
    stB32x2(Bb, sB[1],  0, 64, ldb, tid);  stB32x2(Bb, sB[1], 128, 64, ldb, tid);
  }
  VMCNT(4);               // tile 0 fully resident
  CFENCE; __builtin_amdgcn_s_barrier(); CFENCE;

  bf16x8 af[4][2], bf0[2][2], bf1[2][2];

#define LDA_Q(QM) \
  _Pragma("unroll") \
  for (int mt=0; mt<4; ++mt){ \
    int row = wm*128 + ((QM)*4+mt)*16 + l16; \
    _Pragma("unroll") \
    for (int kc=0; kc<2; ++kc){ \
      int s = (kc*4+quad) ^ (row & 7); \
      af[mt][kc] = *(const bf16x8*)&sAb[row*64 + s*8]; \
    } \
  }

#define LDB_Q(dst, QN) \
  _Pragma("unroll") \
  for (int nt=0; nt<2; ++nt){ \
    int row = wn*64 + ((QN)*2+nt)*16 + l16; \
    _Pragma("unroll") \
    for (int kc=0; kc<2; ++kc){ \
      int s = (kc*4+quad) ^ (row & 7); \
      dst[nt][kc] = *(const bf16x8*)&sBb[row*64 + s*8]; \
    } \
  }

#define PHASE_MFMA(bfX, QM, QN) \
  __builtin_amdgcn_s_setprio(1); \
  _Pragma("unroll") \
  for (int mt=0; mt<4; ++mt){ \
    _Pragma("unroll") \
    for (int kc=0; kc<2; ++kc){ \
      _Pragma("unroll") \
      for (int nt=0; nt<2; ++nt) \
        acc[(QM)*4+mt][(QN)*2+nt] = __builtin_amdgcn_mfma_f32_16x16x32_bf16( \
            af[mt][kc], bfX[nt][kc], acc[(QM)*4+mt][(QN)*2+nt], 0, 0, 0); \
    } \
  } \
  __builtin_amdgcn_s_setprio(0);

  for (int t = 0; t < NT; ++t){
    const int buf = t & 1;
    const u16* sAb = sA[buf];
    const u16* sBb = sB[buf];
    u16* sAc = sA[buf];          // staging into current buffer (tile t+2)
    u16* sBc = sB[buf];
    u16* sAn = sA[buf ^ 1];      // staging into next buffer (tile t+1)
    u16* sBn = sB[buf ^ 1];
    const int kb1 = (t+1) << 6;
    const int kb2 = (t+2) << 6;
    const bool p1 = (t+1 < NT);
    const bool p2 = (t+2 < NT);

    // ---- phase 0: quadrant (0,0); read A qm=0 + B qn=0; stage A-Q13(t+1) ----
    LDA_Q(0)
    LDB_Q(bf0, 0)
    if (p1){ stA64(Ab, sAn, 64, kb1, lda, tid); stA64(Ab, sAn, 192, kb1, lda, tid); }
    CFENCE; __builtin_amdgcn_s_barrier(); CFENCE;
    PHASE_MFMA(bf0, 0, 0)
    if (p1){ VMCNT(6); } else { VMCNT(0); }
    CFENCE; __builtin_amdgcn_s_barrier(); CFENCE;

    // ---- phase 1: quadrant (0,1); read B qn=1; stage B-S1(t+1) ----
    LDB_Q(bf1, 1)
    if (p1){ stB32x2(Bb, sBn, 32, kb1, ldb, tid); stB32x2(Bb, sBn, 160, kb1, ldb, tid); }
    CFENCE; __builtin_amdgcn_s_barrier(); CFENCE;
    PHASE_MFMA(bf1, 0, 1)
    CFENCE; __builtin_amdgcn_s_barrier(); CFENCE;

    // ---- phase 2: quadrant (1,0); read A qm=1; stage A-Q02(t+2) into current buf ----
    LDA_Q(1)
    if (p2){ stA64(Ab, sAc, 0, kb2, lda, tid); stA64(Ab, sAc, 128, kb2, lda, tid); }
    CFENCE; __builtin_amdgcn_s_barrier(); CFENCE;
    PHASE_MFMA(bf0, 1, 0)
    CFENCE; __builtin_amdgcn_s_barrier(); CFENCE;

    // ---- phase 3: quadrant (1,1); no ds_reads; stage B-S0(t+2) into current buf ----
    if (p2){ stB32x2(Bb, sBc, 0, kb2, ldb, tid); stB32x2(Bb, sBc, 128, kb2, ldb, tid); }
    CFENCE; __builtin_amdgcn_s_barrier(); CFENCE;
    PHASE_MFMA(bf1, 1, 1)
    if (p2){ VMCNT(8); } else if (p1){ VMCNT(4); } else { VMCNT(0); }
    CFENCE; __builtin_amdgcn_s_barrier(); CFENCE;
  }

#undef LDA_Q
#undef LDB_Q
#undef PHASE_MFMA

  // epilogue
  #pragma unroll
  for (int mt=0; mt<8; ++mt){
    #pragma unroll
    for (int nt=0; nt<4; ++nt){
      #pragma unroll
      for (int r=0;r<4;++r){
        int row = m0 + wm*128 + mt*16 + quad*4 + r;
        int col = n0 + wn*64 + nt*16 + l16;
        float v = acc[mt][nt][r] + bias[col];
        C[(size_t)row*ldc + col] = f2bf(v);
      }
    }
  }
}

// ---------------- flash attention: one block = (head, 64 q-rows) ----------------
__global__ void __launch_bounds__(256) attn_kernel(
    const u16* __restrict__ qbf, const u16* __restrict__ kbf,
    const u16* __restrict__ h, u16* __restrict__ cat)
{
  __shared__ u16 sQ[64*128];
  __shared__ u16 sK[64*128];
  __shared__ u16 sVT[128*64];
  __shared__ u16 sP[4*16*64];

  const int tid = threadIdx.x;
  const int lane = tid & 63;
  const int wv = tid >> 6;
  const int quad = lane >> 4;
  const int l16 = lane & 15;
  const int l0 = blockIdx.x * 64;
  const int hh = blockIdx.y;

  const u16* qb = qbf + (size_t)hh*SEQ*128;
  const u16* kbp = kbf + (size_t)hh*SEQ*128;

  #pragma unroll
  for (int i=0;i<4;i++){
    int c = i*256 + tid, r = c >> 4, s = c & 15, g = s ^ (r & 15);
    gl_lds16(qb + (size_t)(l0 + r)*128 + g*8, &sQ[c*8]);
  }

  f32x4 accO[8];
  #pragma unroll
  for (int i=0;i<8;i++) accO[i] = zero4();
  float m_i[4] = {-INFINITY,-INFINITY,-INFINITY,-INFINITY};
  float l_i[4] = {0.f,0.f,0.f,0.f};

  for (int kv0 = 0; kv0 < SEQ; kv0 += 64){
    #pragma unroll
    for (int i=0;i<4;i++){
      int c = i*256 + tid, r = c >> 4, s = c & 15, g = s ^ (r & 15);
      gl_lds16(kbp + (size_t)(kv0 + r)*128 + g*8, &sK[c*8]);
    }
    // stage V transposed (VT[d][kv]) straight from h
    #pragma unroll
    for (int i=0;i<8;i++){
      int g4 = i*256 + tid;          // 2048 groups of 4
      int kv = g4 >> 5;
      int d4 = (g4 & 31) * 4;
      const u16* src = h + (size_t)(kv0+kv)*N1 + 6144 + hh*128 + d4;
      u64 vv = *(const u64*)src;
      #pragma unroll
      for (int j=0;j<4;j++){
        int d = d4 + j;
        int s = (kv >> 3) ^ (d & 7);
        sVT[d*64 + s*8 + (kv & 7)] = (u16)(vv >> (16*j));
      }
    }
    __syncthreads();

    // S = Q K^T (this wave's 16 q-rows x 64 kv)
    f32x4 sacc[4];
    #pragma unroll
    for (int i=0;i<4;i++) sacc[i] = zero4();
    #pragma unroll
    for (int kc=0; kc<4; kc++){
      int arow = wv*16 + l16;
      int as = (kc*4 + quad) ^ (arow & 15);
      bf16x8 aF = *(const bf16x8*)&sQ[arow*128 + as*8];
      #pragma unroll
      for (int nt=0; nt<4; nt++){
        int brow = nt*16 + l16;
        int bs = (kc*4 + quad) ^ (brow & 15);
        bf16x8 bF = *(const bf16x8*)&sK[brow*128 + bs*8];
        sacc[nt] = __builtin_amdgcn_mfma_f32_16x16x32_bf16(aF, bF, sacc[nt], 0, 0, 0);
      }
    }
    const float scl = 0.08838834764831845f;  // 1/sqrt(128)
    #pragma unroll
    for (int nt=0; nt<4; nt++){
      #pragma unroll
      for (int r=0;r<4;r++) sacc[nt][r] *= scl;
    }

    // in-register online softmax (rows live in the 16 lanes of a quad)
    float alpha[4];
    #pragma unroll
    for (int r=0;r<4;r++){
      float v = fmaxf(fmaxf(sacc[0][r],sacc[1][r]), fmaxf(sacc[2][r],sacc[3][r]));
      v = fmaxf(v, __shfl_xor(v,1,64));
      v = fmaxf(v, __shfl_xor(v,2,64));
      v = fmaxf(v, __shfl_xor(v,4,64));
      v = fmaxf(v, __shfl_xor(v,8,64));
      float mnew = fmaxf(m_i[r], v);
      alpha[r] = __expf(m_i[r] - mnew);
      m_i[r] = mnew;
    }
    float p[4][4];
    float rsum[4] = {0.f,0.f,0.f,0.f};
    #pragma unroll
    for (int nt=0; nt<4; nt++){
      #pragma unroll
      for (int r=0;r<4;r++){
        float pv = __expf(sacc[nt][r] - m_i[r]);
        p[nt][r] = pv;
        rsum[r] += pv;
      }
    }
    #pragma unroll
    for (int r=0;r<4;r++){
      float s = rsum[r];
      s += __shfl_xor(s,1,64); s += __shfl_xor(s,2,64);
      s += __shfl_xor(s,4,64); s += __shfl_xor(s,8,64);
      l_i[r] = l_i[r]*alpha[r] + s;
    }
    // write P (C-layout -> A-layout via LDS, per-wave region)
    u16* pw = &sP[wv*1024];
    #pragma unroll
    for (int nt=0; nt<4; nt++){
      #pragma unroll
      for (int r=0;r<4;r++){
        int rloc = quad*4 + r;
        int c = nt*16 + l16;
        int slot = (c >> 3) ^ (rloc & 7);
        pw[rloc*64 + slot*8 + (c & 7)] = f2bf(p[nt][r]);
      }
    }
    // rescale O
    #pragma unroll
    for (int dt=0; dt<8; dt++){
      #pragma unroll
      for (int r=0;r<4;r++) accO[dt][r] *= alpha[r];
    }
    // O += P V
    int prow = l16;
    int ps0 = quad ^ (prow & 7);
    int ps1 = (4 + quad) ^ (prow & 7);
    bf16x8 p0 = *(const bf16x8*)&pw[prow*64 + ps0*8];
    bf16x8 p1 = *(const bf16x8*)&pw[prow*64 + ps1*8];
    #pragma unroll
    for (int dt=0; dt<8; dt++){
      int vrow = dt*16 + l16;
      int vs0 = quad ^ (vrow & 7);
      int vs1 = (4 + quad) ^ (vrow & 7);
      bf16x8 v0 = *(const bf16x8*)&sVT[vrow*64 + vs0*8];
      bf16x8 v1 = *(const bf16x8*)&sVT[vrow*64 + vs1*8];
      accO[dt] = __builtin_amdgcn_mfma_f32_16x16x32_bf16(p0, v0, accO[dt], 0, 0, 0);
      accO[dt] = __builtin_amdgcn_mfma_f32_16x16x32_bf16(p1, v1, accO[dt], 0, 0, 0);
    }
    __syncthreads();
  }

  #pragma unroll
  for (int dt=0; dt<8; dt++){
    #pragma unroll
    for (int r=0;r<4;r++){
      int row = l0 + wv*16 + quad*4 + r;
      int col = hh*128 + dt*16 + l16;
      cat[(size_t)row*CATK + col] = f2bf(accO[dt][r] / l_i[r]);
    }
  }
}

// ---------------- launcher ----------------
extern "C" void kernel_launch(void* const* d_in, const int* in_sizes, int n_in,
                              void* d_out, int out_size, void* d_ws, size_t ws_size,
                              hipStream_t stream)
{
  (void)in_sizes; (void)n_in; (void)out_size; (void)ws_size;
  const float* x    = (const float*)d_in[0];
  const float* vec  = (const float*)d_in[1];
  const float* pe   = (const float*)d_in[2];
  const float* modw = (const float*)d_in[3];
  const float* modb = (const float*)d_in[4];
  const float* w1   = (const float*)d_in[5];
  const float* b1   = (const float*)d_in[6];
  const float* w2   = (const float*)d_in[7];
  const float* b2   = (const float*)d_in[8];
  const float* qs   = (const float*)d_in[9];
  const float* ks   = (const float*)d_in[10];
  const float* lqd  = (const float*)d_in[11];
  const float* lqu  = (const float*)d_in[12];
  const float* lkd  = (const float*)d_in[13];
  const float* lku  = (const float*)d_in[14];
  const float* lvd  = (const float*)d_in[15];
  const float* lvu  = (const float*)d_in[16];
  const float* pd   = (const float*)d_in[17];
  const float* pu   = (const float*)d_in[18];
  float* out = (float*)d_out;

  char* ws = (char*)d_ws;
  float* sv    = (float*)(ws + 0);            // 3072 f32
  float* mvec  = (float*)(ws + 12288);        // 9216 f32
  u16* xm      = (u16*)(ws + 49152);          // 2048 x 3072
  u16* U       = (u16*)(ws + 12632064);       // 9216 x 128
  u16* DT      = (u16*)(ws + 14991360);       // 3072 x 128
  u16* pubf    = (u16*)(ws + 15777792);       // 3072 x 64
  u16* pdT     = (u16*)(ws + 16171008);       // 15360 x 64
  u16* w1ext   = (u16*)(ws + 18137088);       // 21504 x 3072
  u16* w2ext   = (u16*)(ws + 150257664);      // 3072 x 15360
  u16* hbuf    = (u16*)(ws + 244629504);      // 2048 x 21504
  u16* qbf     = (u16*)(ws + 332709888);      // 24 x 2048 x 128
  u16* kbf     = (u16*)(ws + 345292800);      // 24 x 2048 x 128
  u16* cat     = (u16*)(ws + 357875712);      // 2048 x 15360

  // weight prep (lora folded: w1' = w1 + U@Dcat, w2' = w2 + pu@pd)
  cast_w1_tail<<<18432,256,0,stream>>>(w1, w1ext);
  build_ustack<<<576,256,0,stream>>>(lqu,lku,lvu,U);
  build_dcatT<<<192,256,0,stream>>>(lqd,lkd,lvd,DT);
  build_pubf<<<96,256,0,stream>>>(pu,pubf);
  build_pdT<<<480,256,0,stream>>>(pd,pdT);
  // w1ext[0:9216] = bf16(U @ DT^T + w1)     M=9216 N=3072 K=128
  gemm_bt<3><<<dim3(72,24),256,0,stream>>>(U,DT,(void*)w1ext,
      128,128,128,K1,K1,nullptr,w1,nullptr);
  // w2ext = bf16(pubf @ pdT^T + w2)         M=3072 N=15360 K=64
  gemm_bt<3><<<dim3(24,120),256,0,stream>>>(pubf,pdT,(void*)w2ext,
      64,64,64,CATK,CATK,nullptr,w2,nullptr);

  // activations
  silu_kernel<<<12,256,0,stream>>>(vec,sv);
  modgemv_kernel<<<9216,256,0,stream>>>(sv,modw,modb,mvec);
  xmod_kernel<<<2048,256,0,stream>>>(x,mvec,xm);
  // h = x_mod @ w1ext^T + b1                M=2048 N=21504 K=3072  (8-phase 256^2)
  gemm256_bias<<<dim3(8,84),512,0,stream>>>(xm,w1ext,hbuf,K1,K1,K1,N1,b1);
  qkv_kernel<<<dim3(2048,24),128,0,stream>>>(hbuf,pe,qs,ks,qbf,kbf);
  gelu_kernel<<<dim3(48,2048),256,0,stream>>>(hbuf,cat);
  attn_kernel<<<dim3(32,24),256,0,stream>>>(qbf,kbf,hbuf,cat);
  // out = x + gate*(cat @ w2ext^T + b2)     M=2048 N=3072 K=15360
  gemm_bt<1><<<dim3(16,24),256,0,stream>>>(cat,w2ext,(void*)out,
      CATK,CATK,CATK,3072,0,b2,x,mvec+6144);
}

// Round 2
// 1510.638 us; speedup vs baseline: 1.2406x; 1.1452x over previous
//
#include <hip/hip_runtime.h>
#include <math.h>

typedef unsigned short u16;
typedef unsigned int u32;
typedef unsigned long long u64;
typedef __attribute__((ext_vector_type(4))) float f32x4;
typedef __attribute__((ext_vector_type(8))) __bf16 bf16x8;

#define SEQ 2048
#define N1 21504      // 3*HID + MLP
#define K1 3072       // HID
#define CATK 15360    // HID + MLP

__device__ __forceinline__ u16 f2bf(float f){
  u32 u = __float_as_uint(f);
  u32 r = u + 0x7FFFu + ((u >> 16) & 1u);
  return (u16)(r >> 16);
}
__device__ __forceinline__ float bf2f(u16 h){
  return __uint_as_float(((u32)h) << 16);
}
__device__ __forceinline__ void gl_lds16(const void* g, void* l){
  __builtin_amdgcn_global_load_lds(
      (const __attribute__((address_space(1))) void*)(size_t)g,
      (__attribute__((address_space(3))) void*)(u32)(size_t)l, 16, 0, 0);
}
__device__ __forceinline__ f32x4 zero4(){ f32x4 z; z[0]=0.f; z[1]=0.f; z[2]=0.f; z[3]=0.f; return z; }

// ---------------- weight prep kernels ----------------
// cast w1 rows [9216,21504) (the MLP part, no lora) to bf16
__global__ void __launch_bounds__(256) cast_w1_tail(
    const float* __restrict__ w1, u16* __restrict__ out)
{
  int gid = blockIdx.x*256 + threadIdx.x;     // 12288*384
  int n = 9216 + gid / 384;
  int k8 = (gid - (n-9216)*384) * 8;
  const float* src = &w1[(size_t)n*K1 + k8];
  union { u16 u[8]; uint4 q; } t;
  #pragma unroll
  for (int j=0;j<8;j++) t.u[j] = f2bf(src[j]);
  *(uint4*)&out[(size_t)n*K1 + k8] = t.q;
}

// U (9216 x 128 bf16): rows n in block b=n/3072 hold up_b[n%3072][:] in cols [32b,32b+32)
__global__ void __launch_bounds__(256) build_ustack(
    const float* __restrict__ lqu, const float* __restrict__ lku,
    const float* __restrict__ lvu, u16* __restrict__ out)
{
  int gid = blockIdx.x*256 + threadIdx.x;     // 9216*16
  int n = gid >> 4;
  int k8 = (gid & 15) * 8;
  int b = n / 3072;
  const float* up = (b==0)? lqu : (b==1)? lku : lvu;
  int nl = n - b*3072;
  union { u16 u[8]; uint4 q; } t;
  #pragma unroll
  for (int j=0;j<8;j++){
    int r = k8 + j - 32*b;
    t.u[j] = (r >= 0 && r < 32) ? f2bf(up[(size_t)nl*32 + r]) : (u16)0;
  }
  *(uint4*)&out[(size_t)n*128 + k8] = t.q;
}

// DT (3072 x 128 bf16): DT[k][r] = down_{r/32}[r%32][k], zero for r>=96
__global__ void __launch_bounds__(256) build_dcatT(
    const float* __restrict__ lqd, const float* __restrict__ lkd,
    const float* __restrict__ lvd, u16* __restrict__ out)
{
  int gid = blockIdx.x*256 + threadIdx.x;     // 3072*16
  int k = gid >> 4;
  int r8 = (gid & 15) * 8;
  union { u16 u[8]; uint4 q; } t;
  #pragma unroll
  for (int j=0;j<8;j++){
    int r = r8 + j;
    float v = (r < 32) ? lqd[(size_t)r*3072 + k]
            : (r < 64) ? lkd[(size_t)(r-32)*3072 + k]
            : (r < 96) ? lvd[(size_t)(r-64)*3072 + k] : 0.f;
    t.u[j] = f2bf(v);
  }
  *(uint4*)&out[(size_t)k*128 + r8] = t.q;
}

// pu (3072 x 64) -> bf16 cast
__global__ void __launch_bounds__(256) build_pubf(
    const float* __restrict__ pu, u16* __restrict__ out)
{
  int gid = blockIdx.x*256 + threadIdx.x;     // 3072*8
  int n = gid >> 3;
  int r8 = (gid & 7) * 8;
  union { u16 u[8]; uint4 q; } t;
  #pragma unroll
  for (int j=0;j<8;j++) t.u[j] = f2bf(pu[(size_t)n*64 + r8 + j]);
  *(uint4*)&out[(size_t)n*64 + r8] = t.q;
}

// pdT (15360 x 64 bf16): pdT[j][r] = pd[r][j]
__global__ void __launch_bounds__(256) build_pdT(
    const float* __restrict__ pd, u16* __restrict__ out)
{
  int gid = blockIdx.x*256 + threadIdx.x;     // 15360*8
  int jj = gid >> 3;
  int r8 = (gid & 7) * 8;
  union { u16 u[8]; uint4 q; } t;
  #pragma unroll
  for (int j=0;j<8;j++) t.u[j] = f2bf(pd[(size_t)(r8+j)*15360 + jj]);
  *(uint4*)&out[(size_t)jj*64 + r8] = t.q;
}

// ---------------- small vector kernels ----------------
__global__ void __launch_bounds__(256) silu_kernel(const float* __restrict__ v, float* __restrict__ sv){
  int i = blockIdx.x*256 + threadIdx.x;
  float x = v[i];
  sv[i] = x / (1.f + __expf(-x));
}

__global__ void __launch_bounds__(256) modgemv_kernel(
    const float* __restrict__ sv, const float* __restrict__ mw,
    const float* __restrict__ mb, float* __restrict__ mout)
{
  int n = blockIdx.x, tid = threadIdx.x;
  const float* wr = mw + (size_t)n*3072;
  float p = 0.f;
  for (int c = tid; c < 3072; c += 256) p += sv[c]*wr[c];
  #pragma unroll
  for (int o=32;o>0;o>>=1) p += __shfl_down(p,o,64);
  __shared__ float red[4];
  if ((tid & 63)==0) red[tid>>6] = p;
  __syncthreads();
  if (tid==0) mout[n] = red[0]+red[1]+red[2]+red[3] + mb[n];
}

__global__ void __launch_bounds__(256) xmod_kernel(
    const float* __restrict__ x, const float* __restrict__ m, u16* __restrict__ xm)
{
  int l = blockIdx.x, tid = threadIdx.x;
  const float* xr = x + (size_t)l*3072;
  float s1=0.f, s2=0.f;
  for (int c=tid;c<3072;c+=256){ float v = xr[c]; s1+=v; s2+=v*v; }
  #pragma unroll
  for (int o=32;o>0;o>>=1){ s1 += __shfl_down(s1,o,64); s2 += __shfl_down(s2,o,64); }
  __shared__ float r1[4], r2[4];
  if ((tid&63)==0){ r1[tid>>6]=s1; r2[tid>>6]=s2; }
  __syncthreads();
  float su = r1[0]+r1[1]+r1[2]+r1[3];
  float sq = r2[0]+r2[1]+r2[2]+r2[3];
  float mu = su / 3072.f;
  float var = sq/3072.f - mu*mu;
  float rstd = rsqrtf(var + 1e-6f);
  u16* orow = xm + (size_t)l*K1;
  for (int c=tid;c<3072;c+=256){
    float v = (xr[c]-mu)*rstd;
    v = v*(1.f + m[3072+c]) + m[c];
    orow[c] = f2bf(v);
  }
}

__global__ void __launch_bounds__(256) gelu_kernel(const u16* __restrict__ h, u16* __restrict__ cat){
  int j = blockIdx.x*256 + threadIdx.x;  // < 12288
  int l = blockIdx.y;
  float v = bf2f(h[(size_t)l*N1 + 9216 + j]);
  float u = 0.7978845608028654f * (v + 0.044715f*v*v*v);
  float t = 1.f - 2.f/(__expf(2.f*u) + 1.f);   // tanh(u)
  cat[(size_t)l*CATK + 3072 + j] = f2bf(0.5f*v*(1.f + t));
}

__global__ void __launch_bounds__(128) qkv_kernel(
    const u16* __restrict__ h, const float* __restrict__ pe,
    const float* __restrict__ qs, const float* __restrict__ ks,
    u16* __restrict__ qbf, u16* __restrict__ kbf)
{
  const int l = blockIdx.x, hh = blockIdx.y, d = threadIdx.x;
  __shared__ float lq[128], lk[128];
  __shared__ float red[4];
  size_t base = (size_t)l*N1 + (size_t)hh*128 + d;
  float qv = bf2f(h[base]);
  float kv = bf2f(h[base + 3072]);
  float pq = qv*qv, pk = kv*kv;
  #pragma unroll
  for (int o=32;o>0;o>>=1){ pq += __shfl_down(pq,o,64); pk += __shfl_down(pk,o,64); }
  if ((d & 63)==0){ red[(d>>6)*2] = pq; red[(d>>6)*2+1] = pk; }
  __syncthreads();
  float rq = rsqrtf((red[0]+red[2])/128.f + 1e-6f);
  float rk = rsqrtf((red[1]+red[3])/128.f + 1e-6f);
  lq[d] = qv*rq*qs[d];
  lk[d] = kv*rk*ks[d];
  __syncthreads();
  int i = d >> 1;
  const float* peb = pe + ((size_t)l*64 + i)*4 + (size_t)(d&1)*2;
  float qo = peb[0]*lq[2*i] + peb[1]*lq[2*i+1];
  float ko = peb[0]*lk[2*i] + peb[1]*lk[2*i+1];
  size_t ob = ((size_t)hh*SEQ + l)*128 + d;
  qbf[ob] = f2bf(qo);
  kbf[ob] = f2bf(ko);
}

// ---------------- GEMM: C[m,n] = sum_k A[m,k]*B[n,k] (+epilogue) ----------------
// MODE 0: bf16 store, +bias
// MODE 1: f32 store, x + gate*(acc+bias)
// MODE 3: bf16 store of (acc + addin_f32[row*ldadd+col])   (weight-fold epilogue)
template<int MODE>
__global__ void __launch_bounds__(256) gemm_bt(
    const u16* __restrict__ A, const u16* __restrict__ B, void* __restrict__ C,
    int K, int lda, int ldb, int ldc, int ldadd,
    const float* __restrict__ bias, const float* __restrict__ xres,
    const float* __restrict__ gate)
{
  __shared__ u16 sA[128*64];
  __shared__ u16 sB[128*64];
  const int tid = threadIdx.x;
  const int lane = tid & 63;
  const int wv = tid >> 6;
  const int quad = lane >> 4;
  const int l16 = lane & 15;
  const int rw = (wv >> 1) * 64;
  const int cw = (wv & 1) * 64;
  const int m0 = blockIdx.x * 128;   // m fastest for B-tile L2 reuse
  const int n0 = blockIdx.y * 128;

  f32x4 acc[4][4];
  #pragma unroll
  for (int i=0;i<4;i++){
    #pragma unroll
    for (int j=0;j<4;j++) acc[i][j] = zero4();
  }

  for (int kb = 0; kb < K; kb += 64){
    #pragma unroll
    for (int i=0;i<4;i++){
      int c = i*256 + tid, r = c >> 3, s = c & 7, g = s ^ (r & 7);
      gl_lds16(A + (size_t)(m0 + r)*lda + kb + g*8, &sA[c*8]);
    }
    #pragma unroll
    for (int i=0;i<4;i++){
      int c = i*256 + tid, r = c >> 3, s = c & 7, g = s ^ (r & 7);
      gl_lds16(B + (size_t)(n0 + r)*ldb + kb + g*8, &sB[c*8]);
    }
    __syncthreads();
    #pragma unroll
    for (int kc=0; kc<2; kc++){
      bf16x8 af[4], bfr[4];
      #pragma unroll
      for (int mt=0; mt<4; mt++){
        int row = rw + mt*16 + l16;
        int s = (kc*4 + quad) ^ (row & 7);
        af[mt] = *(const bf16x8*)&sA[row*64 + s*8];
      }
      #pragma unroll
      for (int nt=0; nt<4; nt++){
        int row = cw + nt*16 + l16;
        int s = (kc*4 + quad) ^ (row & 7);
        bfr[nt] = *(const bf16x8*)&sB[row*64 + s*8];
      }
      #pragma unroll
      for (int mt=0; mt<4; mt++){
        #pragma unroll
        for (int nt=0; nt<4; nt++)
          acc[mt][nt] = __builtin_amdgcn_mfma_f32_16x16x32_bf16(af[mt], bfr[nt], acc[mt][nt], 0, 0, 0);
      }
    }
    __syncthreads();
  }

  #pragma unroll
  for (int mt=0; mt<4; mt++){
    #pragma unroll
    for (int nt=0; nt<4; nt++){
      #pragma unroll
      for (int r=0;r<4;r++){
        int row = m0 + rw + mt*16 + quad*4 + r;
        int col = n0 + cw + nt*16 + l16;
        float v = acc[mt][nt][r];
        if (MODE==0){
          v += bias[col];
          ((u16*)C)[(size_t)row*ldc + col] = f2bf(v);
        } else if (MODE==1){
          v += bias[col];
          ((float*)C)[(size_t)row*ldc + col] = xres[(size_t)row*3072 + col] + gate[col]*v;
        } else {
          v += xres[(size_t)row*ldadd + col];
          ((u16*)C)[(size_t)row*ldc + col] = f2bf(v);
        }
      }
    }
  }
}

// ---------------- 256x256 8-phase pipelined GEMM (T2+T3+T4+T5) ----------------
// C[m,n] = sum_k A[m,k]*B[n,k] + bias[n], bf16 out. K % 64 == 0, M % 256 == 0, N % 256 == 0.
// 8 waves (2M x 4N), per-wave C = 128x64. BK=64, LDS double-buffered (128 KiB).

#define CFENCE asm volatile("" ::: "memory")
#define VMCNT(n) asm volatile("s_waitcnt vmcnt(" #n ")" ::: "memory")

// stage 64 contiguous rows [rb, rb+64) of a 256x64 tile: 512 threads x 16B
__device__ __forceinline__ void stA64(const u16* __restrict__ g, u16* __restrict__ lds,
                                      int rb, int kb, int lda, int tid){
  int ri = tid >> 3, s = tid & 7;
  int R = rb + ri;                    // rb % 8 == 0 -> R&7 == ri&7
  gl_lds16(g + (size_t)R*lda + kb + ((s ^ (R & 7)) << 3), &lds[(R << 6) + (s << 3)]);
}
// stage two 32-row stripes [rb,rb+32) and [rb+64,rb+96): 512 threads x 16B
__device__ __forceinline__ void stB32x2(const u16* __restrict__ g, u16* __restrict__ lds,
                                        int rb, int kb, int ldb, int tid){
  int ri = tid >> 3, s = tid & 7;
  int R = rb + (ri & 31) + ((ri >> 5) << 6);
  gl_lds16(g + (size_t)R*ldb + kb + ((s ^ (R & 7)) << 3), &lds[(R << 6) + (s << 3)]);
}

__global__ void __launch_bounds__(512, 2) gemm256_bias(
    const u16* __restrict__ A, const u16* __restrict__ B, u16* __restrict__ C,
    int K, int lda, int ldb, int ldc, const float* __restrict__ bias)
{
  __shared__ u16 sA[2][256*64];
  __shared__ u16 sB[2][256*64];
  const int tid  = threadIdx.x;
  const int lane = tid & 63;
  const int wv   = tid >> 6;
  const int quad = lane >> 4;
  const int l16  = lane & 15;
  const int wm   = wv >> 2;          // 0..1
  const int wn   = wv & 3;           // 0..3
  const int m0   = blockIdx.x * 256;
  const int n0   = blockIdx.y * 256;
  const u16* Ab  = A + (size_t)m0 * lda;
  const u16* Bb  = B + (size_t)n0 * ldb;
  const int NT   = K >> 6;

  f32x4 acc[8][4];
  #pragma unroll
  for (int i=0;i<8;i++){
    #pragma unroll
    for (int j=0;j<4;j++) acc[i][j] = zero4();
  }

  // prologue
  stA64 (Ab, sA[0],   0, 0, lda, tid);  stA64 (Ab, sA[0], 128, 0, lda, tid);
  stB32x2(Bb, sB[0],  0, 0, ldb, tid);  stB32x2(Bb, sB[0], 128, 0, ldb, tid);
  stA64 (Ab, sA[0],  64, 0, lda, tid);  stA64 (Ab, sA[0], 192, 0, lda, tid);
  stB32x2(Bb, sB[0], 32, 0, ldb, tid);  stB32x2(Bb, sB[0], 160, 0, ldb, tid);
  if (NT > 1){
    stA64 (Ab, sA[1],   0, 64, lda, tid);  stA64 (Ab, sA[1], 128, 64, lda, tid);
    stB32x2(Bb, sB[1],  0, 64, ldb, tid);  stB32x2(Bb, sB[1], 128, 64, ldb, tid);
  }
  VMCNT(4);               // tile 0 fully resident
  CFENCE; __builtin_amdgcn_s_barrier(); CFENCE;

  bf16x8 af[4][2], bf0[2][2], bf1[2][2];

#define LDA_Q(QM) \
  _Pragma("unroll") \
  for (int mt=0; mt<4; ++mt){ \
    int row = wm*128 + ((QM)*4+mt)*16 + l16; \
    _Pragma("unroll") \
    for (int kc=0; kc<2; ++kc){ \
      int s = (kc*4+quad) ^ (row & 7); \
      af[mt][kc] = *(const bf16x8*)&sAb[row*64 + s*8]; \
    } \
  }

#define LDB_Q(dst, QN) \
  _Pragma("unroll") \
  for (int nt=0; nt<2; ++nt){ \
    int row = wn*64 + ((QN)*2+nt)*16 + l16; \
    _Pragma("unroll") \
    for (int kc=0; kc<2; ++kc){ \
      int s = (kc*4+quad) ^ (row & 7); \
      dst[nt][kc] = *(const bf16x8*)&sBb[row*64 + s*8]; \
    } \
  }

#define PHASE_MFMA(bfX, QM, QN) \
  __builtin_amdgcn_s_setprio(1); \
  _Pragma("unroll") \
  for (int mt=0; mt<4; ++mt){ \
    _Pragma("unroll") \
    for (int kc=0; kc<2; ++kc){ \
      _Pragma("unroll") \
      for (int nt=0; nt<2; ++nt) \
        acc[(QM)*4+mt][(QN)*2+nt] = __builtin_amdgcn_mfma_f32_16x16x32_bf16( \
            af[mt][kc], bfX[nt][kc], acc[(QM)*4+mt][(QN)*2+nt], 0, 0, 0); \
    } \
  } \
  __builtin_amdgcn_s_setprio(0);

  for (int t = 0; t < NT; ++t){
    const int buf = t & 1;
    const u16* sAb = sA[buf];
    const u16* sBb = sB[buf];
    u16* sAc = sA[buf];          // staging into current buffer (tile t+2)
    u16* sBc = sB[buf];
    u16* sAn = sA[buf ^ 1];      // staging into next buffer (tile t+1)
    u16* sBn = sB[buf ^ 1];
    const int kb1 = (t+1) << 6;
    const int kb2 = (t+2) << 6;
    const bool p1 = (t+1 < NT);
    const bool p2 = (t+2 < NT);

    // ---- phase 0: quadrant (0,0); stage A-Q13(t+1) ----
    LDA_Q(0)
    LDB_Q(bf0, 0)
    if (p1){ stA64(Ab, sAn, 64, kb1, lda, tid); stA64(Ab, sAn, 192, kb1, lda, tid); }
    CFENCE; __builtin_amdgcn_s_barrier(); CFENCE;
    PHASE_MFMA(bf0, 0, 0)
    if (p1){ VMCNT(6); } else { VMCNT(0); }
    CFENCE; __builtin_amdgcn_s_barrier(); CFENCE;

    // ---- phase 1: quadrant (0,1); stage B-S1(t+1) ----
    LDB_Q(bf1, 1)
    if (p1){ stB32x2(Bb, sBn, 32, kb1, ldb, tid); stB32x2(Bb, sBn, 160, kb1, ldb, tid); }
    CFENCE; __builtin_amdgcn_s_barrier(); CFENCE;
    PHASE_MFMA(bf1, 0, 1)
    CFENCE; __builtin_amdgcn_s_barrier(); CFENCE;

    // ---- phase 2: quadrant (1,0); stage A-Q02(t+2) into current buf ----
    LDA_Q(1)
    if (p2){ stA64(Ab, sAc, 0, kb2, lda, tid); stA64(Ab, sAc, 128, kb2, lda, tid); }
    CFENCE; __builtin_amdgcn_s_barrier(); CFENCE;
    PHASE_MFMA(bf0, 1, 0)
    CFENCE; __builtin_amdgcn_s_barrier(); CFENCE;

    // ---- phase 3: quadrant (1,1); stage B-S0(t+2) into current buf ----
    if (p2){ stB32x2(Bb, sBc, 0, kb2, ldb, tid); stB32x2(Bb, sBc, 128, kb2, ldb, tid); }
    CFENCE; __builtin_amdgcn_s_barrier(); CFENCE;
    PHASE_MFMA(bf1, 1, 1)
    if (p2){ VMCNT(8); } else if (p1){ VMCNT(4); } else { VMCNT(0); }
    CFENCE; __builtin_amdgcn_s_barrier(); CFENCE;
  }

#undef LDA_Q
#undef LDB_Q
#undef PHASE_MFMA

  // epilogue
  #pragma unroll
  for (int mt=0; mt<8; ++mt){
    #pragma unroll
    for (int nt=0; nt<4; ++nt){
      #pragma unroll
      for (int r=0;r<4;++r){
        int row = m0 + wm*128 + mt*16 + quad*4 + r;
        int col = n0 + wn*64 + nt*16 + l16;
        float v = acc[mt][nt][r] + bias[col];
        C[(size_t)row*ldc + col] = f2bf(v);
      }
    }
  }
}

// ---------------- flash attention: one block = (head, 64 q-rows) ----------------
// V staging: in-register 4xd transpose from coalesced u64 loads, 4x ds_write_b128
// per thread with swizzle s = kv8 ^ (d&7) ^ ((d>>3)&7) (all 32 banks covered per
// write instruction, 8 lanes / 4-bank group = phased-optimal).
__global__ void __launch_bounds__(256) attn_kernel(
    const u16* __restrict__ qbf, const u16* __restrict__ kbf,
    const u16* __restrict__ h, u16* __restrict__ cat)
{
  __shared__ u16 sQ[64*128];
  __shared__ u16 sK[64*128];
  __shared__ u16 sVT[128*64];
  __shared__ u16 sP[4*16*64];

  const int tid = threadIdx.x;
  const int lane = tid & 63;
  const int wv = tid >> 6;
  const int quad = lane >> 4;
  const int l16 = lane & 15;
  const int l0 = blockIdx.x * 64;
  const int hh = blockIdx.y;

  const u16* qb = qbf + (size_t)hh*SEQ*128;
  const u16* kbp = kbf + (size_t)hh*SEQ*128;

  #pragma unroll
  for (int i=0;i<4;i++){
    int c = i*256 + tid, r = c >> 4, s = c & 15, g = s ^ (r & 15);
    gl_lds16(qb + (size_t)(l0 + r)*128 + g*8, &sQ[c*8]);
  }

  // per-thread V staging geometry (constant across tiles)
  const int kv8 = tid >> 5;            // 0..7 (kv group of 8 rows)
  const int d4  = (tid & 31) * 4;      // 0..124 (4 consecutive d)

  f32x4 accO[8];
  #pragma unroll
  for (int i=0;i<8;i++) accO[i] = zero4();
  float m_i[4] = {-INFINITY,-INFINITY,-INFINITY,-INFINITY};
  float l_i[4] = {0.f,0.f,0.f,0.f};

  for (int kv0 = 0; kv0 < SEQ; kv0 += 64){
    #pragma unroll
    for (int i=0;i<4;i++){
      int c = i*256 + tid, r = c >> 4, s = c & 15, g = s ^ (r & 15);
      gl_lds16(kbp + (size_t)(kv0 + r)*128 + g*8, &sK[c*8]);
    }
    // stage V transposed: 8 coalesced u64 loads (8 kv rows x 4 d), in-register
    // transpose, 4x ds_write_b128
    {
      const u16* src = h + (size_t)(kv0 + kv8*8)*N1 + 6144 + (size_t)hh*128 + d4;
      u64 vv[8];
      #pragma unroll
      for (int j=0;j<8;j++) vv[j] = *(const u64*)(src + (size_t)j*N1);
      #pragma unroll
      for (int jd=0;jd<4;jd++){
        int d = d4 + jd;
        union { u16 u[8]; uint4 q; } t;
        #pragma unroll
        for (int j=0;j<8;j++) t.u[j] = (u16)(vv[j] >> (16*jd));
        int s = kv8 ^ (d & 7) ^ ((d >> 3) & 7);
        *(uint4*)&sVT[d*64 + s*8] = t.q;
      }
    }
    __syncthreads();

    // S = Q K^T (this wave's 16 q-rows x 64 kv)
    f32x4 sacc[4];
    #pragma unroll
    for (int i=0;i<4;i++) sacc[i] = zero4();
    __builtin_amdgcn_s_setprio(1);
    #pragma unroll
    for (int kc=0; kc<4; kc++){
      int arow = wv*16 + l16;
      int as = (kc*4 + quad) ^ (arow & 15);
      bf16x8 aF = *(const bf16x8*)&sQ[arow*128 + as*8];
      #pragma unroll
      for (int nt=0; nt<4; nt++){
        int brow = nt*16 + l16;
        int bs = (kc*4 + quad) ^ (brow & 15);
        bf16x8 bF = *(const bf16x8*)&sK[brow*128 + bs*8];
        sacc[nt] = __builtin_amdgcn_mfma_f32_16x16x32_bf16(aF, bF, sacc[nt], 0, 0, 0);
      }
    }
    __builtin_amdgcn_s_setprio(0);
    const float scl = 0.08838834764831845f;  // 1/sqrt(128)
    #pragma unroll
    for (int nt=0; nt<4; nt++){
      #pragma unroll
      for (int r=0;r<4;r++) sacc[nt][r] *= scl;
    }

    // in-register online softmax (rows live in the 16 lanes of a quad)
    float alpha[4];
    #pragma unroll
    for (int r=0;r<4;r++){
      float v = fmaxf(fmaxf(sacc[0][r],sacc[1][r]), fmaxf(sacc[2][r],sacc[3][r]));
      v = fmaxf(v, __shfl_xor(v,1,64));
      v = fmaxf(v, __shfl_xor(v,2,64));
      v = fmaxf(v, __shfl_xor(v,4,64));
      v = fmaxf(v, __shfl_xor(v,8,64));
      float mnew = fmaxf(m_i[r], v);
      alpha[r] = __expf(m_i[r] - mnew);
      m_i[r] = mnew;
    }
    float p[4][4];
    float rsum[4] = {0.f,0.f,0.f,0.f};
    #pragma unroll
    for (int nt=0; nt<4; nt++){
      #pragma unroll
      for (int r=0;r<4;r++){
        float pv = __expf(sacc[nt][r] - m_i[r]);
        p[nt][r] = pv;
        rsum[r] += pv;
      }
    }
    #pragma unroll
    for (int r=0;r<4;r++){
      float s = rsum[r];
      s += __shfl_xor(s,1,64); s += __shfl_xor(s,2,64);
      s += __shfl_xor(s,4,64); s += __shfl_xor(s,8,64);
      l_i[r] = l_i[r]*alpha[r] + s;
    }
    // write P (C-layout -> A-layout via LDS, per-wave region)
    u16* pw = &sP[wv*1024];
    #pragma unroll
    for (int nt=0; nt<4; nt++){
      #pragma unroll
      for (int r=0;r<4;r++){
        int rloc = quad*4 + r;
        int c = nt*16 + l16;
        int slot = (c >> 3) ^ (rloc & 7);
        pw[rloc*64 + slot*8 + (c & 7)] = f2bf(p[nt][r]);
      }
    }
    // rescale O
    #pragma unroll
    for (int dt=0; dt<8; dt++){
      #pragma unroll
      for (int r=0;r<4;r++) accO[dt][r] *= alpha[r];
    }
    // O += P V
    int prow = l16;
    int ps0 = quad ^ (prow & 7);
    int ps1 = (4 + quad) ^ (prow & 7);
    bf16x8 p0 = *(const bf16x8*)&pw[prow*64 + ps0*8];
    bf16x8 p1 = *(const bf16x8*)&pw[prow*64 + ps1*8];
    __builtin_amdgcn_s_setprio(1);
    #pragma unroll
    for (int dt=0; dt<8; dt++){
      int vrow = dt*16 + l16;
      int hs = (vrow >> 3) & 7;
      int vs0 = (quad ^ (vrow & 7) ^ hs);
      int vs1 = ((4 + quad) ^ (vrow & 7) ^ hs);
      bf16x8 v0 = *(const bf16x8*)&sVT[vrow*64 + vs0*8];
      bf16x8 v1 = *(const bf16x8*)&sVT[vrow*64 + vs1*8];
      accO[dt] = __builtin_amdgcn_mfma_f32_16x16x32_bf16(p0, v0, accO[dt], 0, 0, 0);
      accO[dt] = __builtin_amdgcn_mfma_f32_16x16x32_bf16(p1, v1, accO[dt], 0, 0, 0);
    }
    __builtin_amdgcn_s_setprio(0);
    __syncthreads();
  }

  #pragma unroll
  for (int dt=0; dt<8; dt++){
    #pragma unroll
    for (int r=0;r<4;r++){
      int row = l0 + wv*16 + quad*4 + r;
      int col = hh*128 + dt*16 + l16;
      cat[(size_t)row*CATK + col] = f2bf(accO[dt][r] / l_i[r]);
    }
  }
}

// ---------------- launcher ----------------
extern "C" void kernel_launch(void* const* d_in, const int* in_sizes, int n_in,
                              void* d_out, int out_size, void* d_ws, size_t ws_size,
                              hipStream_t stream)
{
  (void)in_sizes; (void)n_in; (void)out_size; (void)ws_size;
  const float* x    = (const float*)d_in[0];
  const float* vec  = (const float*)d_in[1];
  const float* pe   = (const float*)d_in[2];
  const float* modw = (const float*)d_in[3];
  const float* modb = (const float*)d_in[4];
  const float* w1   = (const float*)d_in[5];
  const float* b1   = (const float*)d_in[6];
  const float* w2   = (const float*)d_in[7];
  const float* b2   = (const float*)d_in[8];
  const float* qs   = (const float*)d_in[9];
  const float* ks   = (const float*)d_in[10];
  const float* lqd  = (const float*)d_in[11];
  const float* lqu  = (const float*)d_in[12];
  const float* lkd  = (const float*)d_in[13];
  const float* lku  = (const float*)d_in[14];
  const float* lvd  = (const float*)d_in[15];
  const float* lvu  = (const float*)d_in[16];
  const float* pd   = (const float*)d_in[17];
  const float* pu   = (const float*)d_in[18];
  float* out = (float*)d_out;

  char* ws = (char*)d_ws;
  float* sv    = (float*)(ws + 0);            // 3072 f32
  float* mvec  = (float*)(ws + 12288);        // 9216 f32
  u16* xm      = (u16*)(ws + 49152);          // 2048 x 3072
  u16* U       = (u16*)(ws + 12632064);       // 9216 x 128
  u16* DT      = (u16*)(ws + 14991360);       // 3072 x 128
  u16* pubf    = (u16*)(ws + 15777792);       // 3072 x 64
  u16* pdT     = (u16*)(ws + 16171008);       // 15360 x 64
  u16* w1ext   = (u16*)(ws + 18137088);       // 21504 x 3072
  u16* w2ext   = (u16*)(ws + 150257664);      // 3072 x 15360
  u16* hbuf    = (u16*)(ws + 244629504);      // 2048 x 21504
  u16* qbf     = (u16*)(ws + 332709888);      // 24 x 2048 x 128
  u16* kbf     = (u16*)(ws + 345292800);      // 24 x 2048 x 128
  u16* cat     = (u16*)(ws + 357875712);      // 2048 x 15360

  // weight prep (lora folded: w1' = w1 + U@Dcat, w2' = w2 + pu@pd)
  cast_w1_tail<<<18432,256,0,stream>>>(w1, w1ext);
  build_ustack<<<576,256,0,stream>>>(lqu,lku,lvu,U);
  build_dcatT<<<192,256,0,stream>>>(lqd,lkd,lvd,DT);
  build_pubf<<<96,256,0,stream>>>(pu,pubf);
  build_pdT<<<480,256,0,stream>>>(pd,pdT);
  // w1ext[0:9216] = bf16(U @ DT^T + w1)     M=9216 N=3072 K=128
  gemm_bt<3><<<dim3(72,24),256,0,stream>>>(U,DT,(void*)w1ext,
      128,128,128,K1,K1,nullptr,w1,nullptr);
  // w2ext = bf16(pubf @ pdT^T + w2)         M=3072 N=15360 K=64
  gemm_bt<3><<<dim3(24,120),256,0,stream>>>(pubf,pdT,(void*)w2ext,
      64,64,64,CATK,CATK,nullptr,w2,nullptr);

  // activations
  silu_kernel<<<12,256,0,stream>>>(vec,sv);
  modgemv_kernel<<<9216,256,0,stream>>>(sv,modw,modb,mvec);
  xmod_kernel<<<2048,256,0,stream>>>(x,mvec,xm);
  // h = x_mod @ w1ext^T + b1                M=2048 N=21504 K=3072  (8-phase 256^2)
  gemm256_bias<<<dim3(8,84),512,0,stream>>>(xm,w1ext,hbuf,K1,K1,K1,N1,b1);
  qkv_kernel<<<dim3(2048,24),128,0,stream>>>(hbuf,pe,qs,ks,qbf,kbf);
  gelu_kernel<<<dim3(48,2048),256,0,stream>>>(hbuf,cat);
  attn_kernel<<<dim3(32,24),256,0,stream>>>(qbf,kbf,hbuf,cat);
  // out = x + gate*(cat @ w2ext^T + b2)     M=2048 N=3072 K=15360
  gemm_bt<1><<<dim3(16,24),256,0,stream>>>(cat,w2ext,(void*)out,
      CATK,CATK,CATK,3072,0,b2,x,mvec+6144);
}

// Round 4
// 1496.921 us; speedup vs baseline: 1.2519x; 1.0092x over previous
//
#include <hip/hip_runtime.h>
#include <math.h>

typedef unsigned short u16;
typedef unsigned int u32;
typedef unsigned long long u64;
typedef __attribute__((ext_vector_type(4))) float f32x4;
typedef __attribute__((ext_vector_type(8))) __bf16 bf16x8;

#define SEQ 2048
#define N1 21504      // 3*HID + MLP
#define K1 3072       // HID
#define CATK 15360    // HID + MLP

__device__ __forceinline__ u16 f2bf(float f){
  u32 u = __float_as_uint(f);
  u32 r = u + 0x7FFFu + ((u >> 16) & 1u);
  return (u16)(r >> 16);
}
__device__ __forceinline__ float bf2f(u16 h){
  return __uint_as_float(((u32)h) << 16);
}
__device__ __forceinline__ void gl_lds16(const void* g, void* l){
  __builtin_amdgcn_global_load_lds(
      (const __attribute__((address_space(1))) void*)(size_t)g,
      (__attribute__((address_space(3))) void*)(u32)(size_t)l, 16, 0, 0);
}
__device__ __forceinline__ f32x4 zero4(){ f32x4 z; z[0]=0.f; z[1]=0.f; z[2]=0.f; z[3]=0.f; return z; }

// ---------------- weight prep kernels ----------------
// cast w1 rows [9216,21504) (the MLP part, no lora) to bf16
__global__ void __launch_bounds__(256) cast_w1_tail(
    const float* __restrict__ w1, u16* __restrict__ out)
{
  int gid = blockIdx.x*256 + threadIdx.x;     // 12288*384
  int n = 9216 + gid / 384;
  int k8 = (gid - (n-9216)*384) * 8;
  const float* src = &w1[(size_t)n*K1 + k8];
  union { u16 u[8]; uint4 q; } t;
  #pragma unroll
  for (int j=0;j<8;j++) t.u[j] = f2bf(src[j]);
  *(uint4*)&out[(size_t)n*K1 + k8] = t.q;
}

// U (9216 x 128 bf16): rows n in block b=n/3072 hold up_b[n%3072][:] in cols [32b,32b+32)
__global__ void __launch_bounds__(256) build_ustack(
    const float* __restrict__ lqu, const float* __restrict__ lku,
    const float* __restrict__ lvu, u16* __restrict__ out)
{
  int gid = blockIdx.x*256 + threadIdx.x;     // 9216*16
  int n = gid >> 4;
  int k8 = (gid & 15) * 8;
  int b = n / 3072;
  const float* up = (b==0)? lqu : (b==1)? lku : lvu;
  int nl = n - b*3072;
  union { u16 u[8]; uint4 q; } t;
  #pragma unroll
  for (int j=0;j<8;j++){
    int r = k8 + j - 32*b;
    t.u[j] = (r >= 0 && r < 32) ? f2bf(up[(size_t)nl*32 + r]) : (u16)0;
  }
  *(uint4*)&out[(size_t)n*128 + k8] = t.q;
}

// DT (3072 x 128 bf16): DT[k][r] = down_{r/32}[r%32][k], zero for r>=96
__global__ void __launch_bounds__(256) build_dcatT(
    const float* __restrict__ lqd, const float* __restrict__ lkd,
    const float* __restrict__ lvd, u16* __restrict__ out)
{
  int gid = blockIdx.x*256 + threadIdx.x;     // 3072*16
  int k = gid >> 4;
  int r8 = (gid & 15) * 8;
  union { u16 u[8]; uint4 q; } t;
  #pragma unroll
  for (int j=0;j<8;j++){
    int r = r8 + j;
    float v = (r < 32) ? lqd[(size_t)r*3072 + k]
            : (r < 64) ? lkd[(size_t)(r-32)*3072 + k]
            : (r < 96) ? lvd[(size_t)(r-64)*3072 + k] : 0.f;
    t.u[j] = f2bf(v);
  }
  *(uint4*)&out[(size_t)k*128 + r8] = t.q;
}

// pu (3072 x 64) -> bf16 cast
__global__ void __launch_bounds__(256) build_pubf(
    const float* __restrict__ pu, u16* __restrict__ out)
{
  int gid = blockIdx.x*256 + threadIdx.x;     // 3072*8
  int n = gid >> 3;
  int r8 = (gid & 7) * 8;
  union { u16 u[8]; uint4 q; } t;
  #pragma unroll
  for (int j=0;j<8;j++) t.u[j] = f2bf(pu[(size_t)n*64 + r8 + j]);
  *(uint4*)&out[(size_t)n*64 + r8] = t.q;
}

// pdT (15360 x 64 bf16): pdT[j][r] = pd[r][j]
__global__ void __launch_bounds__(256) build_pdT(
    const float* __restrict__ pd, u16* __restrict__ out)
{
  int gid = blockIdx.x*256 + threadIdx.x;     // 15360*8
  int jj = gid >> 3;
  int r8 = (gid & 7) * 8;
  union { u16 u[8]; uint4 q; } t;
  #pragma unroll
  for (int j=0;j<8;j++) t.u[j] = f2bf(pd[(size_t)(r8+j)*15360 + jj]);
  *(uint4*)&out[(size_t)jj*64 + r8] = t.q;
}

// ---------------- small vector kernels ----------------
__global__ void __launch_bounds__(256) silu_kernel(const float* __restrict__ v, float* __restrict__ sv){
  int i = blockIdx.x*256 + threadIdx.x;
  float x = v[i];
  sv[i] = x / (1.f + __expf(-x));
}

__global__ void __launch_bounds__(256) modgemv_kernel(
    const float* __restrict__ sv, const float* __restrict__ mw,
    const float* __restrict__ mb, float* __restrict__ mout)
{
  int n = blockIdx.x, tid = threadIdx.x;
  const float* wr = mw + (size_t)n*3072;
  float p = 0.f;
  for (int c = tid; c < 3072; c += 256) p += sv[c]*wr[c];
  #pragma unroll
  for (int o=32;o>0;o>>=1) p += __shfl_down(p,o,64);
  __shared__ float red[4];
  if ((tid & 63)==0) red[tid>>6] = p;
  __syncthreads();
  if (tid==0) mout[n] = red[0]+red[1]+red[2]+red[3] + mb[n];
}

__global__ void __launch_bounds__(256) xmod_kernel(
    const float* __restrict__ x, const float* __restrict__ m, u16* __restrict__ xm)
{
  int l = blockIdx.x, tid = threadIdx.x;
  const float* xr = x + (size_t)l*3072;
  float s1=0.f, s2=0.f;
  for (int c=tid;c<3072;c+=256){ float v = xr[c]; s1+=v; s2+=v*v; }
  #pragma unroll
  for (int o=32;o>0;o>>=1){ s1 += __shfl_down(s1,o,64); s2 += __shfl_down(s2,o,64); }
  __shared__ float r1[4], r2[4];
  if ((tid&63)==0){ r1[tid>>6]=s1; r2[tid>>6]=s2; }
  __syncthreads();
  float su = r1[0]+r1[1]+r1[2]+r1[3];
  float sq = r2[0]+r2[1]+r2[2]+r2[3];
  float mu = su / 3072.f;
  float var = sq/3072.f - mu*mu;
  float rstd = rsqrtf(var + 1e-6f);
  u16* orow = xm + (size_t)l*K1;
  for (int c=tid;c<3072;c+=256){
    float v = (xr[c]-mu)*rstd;
    v = v*(1.f + m[3072+c]) + m[c];
    orow[c] = f2bf(v);
  }
}

__global__ void __launch_bounds__(256) gelu_kernel(const u16* __restrict__ h, u16* __restrict__ cat){
  int j = blockIdx.x*256 + threadIdx.x;  // < 12288
  int l = blockIdx.y;
  float v = bf2f(h[(size_t)l*N1 + 9216 + j]);
  float u = 0.7978845608028654f * (v + 0.044715f*v*v*v);
  float t = 1.f - 2.f/(__expf(2.f*u) + 1.f);   // tanh(u)
  cat[(size_t)l*CATK + 3072 + j] = f2bf(0.5f*v*(1.f + t));
}

__global__ void __launch_bounds__(128) qkv_kernel(
    const u16* __restrict__ h, const float* __restrict__ pe,
    const float* __restrict__ qs, const float* __restrict__ ks,
    u16* __restrict__ qbf, u16* __restrict__ kbf)
{
  const int l = blockIdx.x, hh = blockIdx.y, d = threadIdx.x;
  __shared__ float lq[128], lk[128];
  __shared__ float red[4];
  size_t base = (size_t)l*N1 + (size_t)hh*128 + d;
  float qv = bf2f(h[base]);
  float kv = bf2f(h[base + 3072]);
  float pq = qv*qv, pk = kv*kv;
  #pragma unroll
  for (int o=32;o>0;o>>=1){ pq += __shfl_down(pq,o,64); pk += __shfl_down(pk,o,64); }
  if ((d & 63)==0){ red[(d>>6)*2] = pq; red[(d>>6)*2+1] = pk; }
  __syncthreads();
  float rq = rsqrtf((red[0]+red[2])/128.f + 1e-6f);
  float rk = rsqrtf((red[1]+red[3])/128.f + 1e-6f);
  lq[d] = qv*rq*qs[d];
  lk[d] = kv*rk*ks[d];
  __syncthreads();
  int i = d >> 1;
  const float* peb = pe + ((size_t)l*64 + i)*4 + (size_t)(d&1)*2;
  float qo = peb[0]*lq[2*i] + peb[1]*lq[2*i+1];
  float ko = peb[0]*lk[2*i] + peb[1]*lk[2*i+1];
  size_t ob = ((size_t)hh*SEQ + l)*128 + d;
  qbf[ob] = f2bf(qo);
  kbf[ob] = f2bf(ko);
}

// zero a f32 buffer (count must be grid*256*4)
__global__ void __launch_bounds__(256) zero_f32(float* __restrict__ p){
  ((f32x4*)p)[blockIdx.x*256 + threadIdx.x] = zero4();
}

// out = x + gate[col]*(S + b2[col]) over 2048x3072, f32x4-vectorized
// grid (2048, 3) x 256: row = blockIdx.x, c4 = blockIdx.y*256+tid (768 groups/row)
__global__ void __launch_bounds__(256) final_epilogue(
    const float* __restrict__ S, const float* __restrict__ x,
    const float* __restrict__ gate, const float* __restrict__ b2,
    float* __restrict__ out)
{
  int row = blockIdx.x;
  int c4  = blockIdx.y*256 + threadIdx.x;   // 0..767
  size_t i = (size_t)row*768 + c4;          // f32x4 index
  int col4 = c4 * 4;
  f32x4 s = ((const f32x4*)S)[i];
  f32x4 xv = ((const f32x4*)x)[i];
  f32x4 g = *(const f32x4*)&gate[col4];
  f32x4 b = *(const f32x4*)&b2[col4];
  f32x4 o;
  #pragma unroll
  for (int j=0;j<4;j++) o[j] = xv[j] + g[j]*(s[j] + b[j]);
  ((f32x4*)out)[i] = o;
}

// ---------------- GEMM: C[m,n] = sum_k A[m,k]*B[n,k] (+epilogue) ----------------
// MODE 0: bf16 store, +bias
// MODE 3: bf16 store of (acc + addin_f32[row*ldadd+col])   (weight-fold epilogue)
template<int MODE>
__global__ void __launch_bounds__(256) gemm_bt(
    const u16* __restrict__ A, const u16* __restrict__ B, void* __restrict__ C,
    int K, int lda, int ldb, int ldc, int ldadd,
    const float* __restrict__ bias, const float* __restrict__ xres,
    const float* __restrict__ gate)
{
  __shared__ u16 sA[128*64];
  __shared__ u16 sB[128*64];
  const int tid = threadIdx.x;
  const int lane = tid & 63;
  const int wv = tid >> 6;
  const int quad = lane >> 4;
  const int l16 = lane & 15;
  const int rw = (wv >> 1) * 64;
  const int cw = (wv & 1) * 64;
  const int m0 = blockIdx.x * 128;   // m fastest for B-tile L2 reuse
  const int n0 = blockIdx.y * 128;

  f32x4 acc[4][4];
  #pragma unroll
  for (int i=0;i<4;i++){
    #pragma unroll
    for (int j=0;j<4;j++) acc[i][j] = zero4();
  }

  for (int kb = 0; kb < K; kb += 64){
    #pragma unroll
    for (int i=0;i<4;i++){
      int c = i*256 + tid, r = c >> 3, s = c & 7, g = s ^ (r & 7);
      gl_lds16(A + (size_t)(m0 + r)*lda + kb + g*8, &sA[c*8]);
    }
    #pragma unroll
    for (int i=0;i<4;i++){
      int c = i*256 + tid, r = c >> 3, s = c & 7, g = s ^ (r & 7);
      gl_lds16(B + (size_t)(n0 + r)*ldb + kb + g*8, &sB[c*8]);
    }
    __syncthreads();
    #pragma unroll
    for (int kc=0; kc<2; kc++){
      bf16x8 af[4], bfr[4];
      #pragma unroll
      for (int mt=0; mt<4; mt++){
        int row = rw + mt*16 + l16;
        int s = (kc*4 + quad) ^ (row & 7);
        af[mt] = *(const bf16x8*)&sA[row*64 + s*8];
      }
      #pragma unroll
      for (int nt=0; nt<4; nt++){
        int row = cw + nt*16 + l16;
        int s = (kc*4 + quad) ^ (row & 7);
        bfr[nt] = *(const bf16x8*)&sB[row*64 + s*8];
      }
      #pragma unroll
      for (int mt=0; mt<4; mt++){
        #pragma unroll
        for (int nt=0; nt<4; nt++)
          acc[mt][nt] = __builtin_amdgcn_mfma_f32_16x16x32_bf16(af[mt], bfr[nt], acc[mt][nt], 0, 0, 0);
      }
    }
    __syncthreads();
  }

  #pragma unroll
  for (int mt=0; mt<4; mt++){
    #pragma unroll
    for (int nt=0; nt<4; nt++){
      #pragma unroll
      for (int r=0;r<4;r++){
        int row = m0 + rw + mt*16 + quad*4 + r;
        int col = n0 + cw + nt*16 + l16;
        float v = acc[mt][nt][r];
        if (MODE==0){
          v += bias[col];
          ((u16*)C)[(size_t)row*ldc + col] = f2bf(v);
        } else {
          v += xres[(size_t)row*ldadd + col];
          ((u16*)C)[(size_t)row*ldc + col] = f2bf(v);
        }
      }
    }
  }
}

// ---------------- 256x256 8-phase pipelined GEMM (T2+T3+T4+T5) ----------------
// C[m,n] = sum_k A[m,k]*B[n,k] + bias[n], bf16 out. K % 64 == 0, M % 256 == 0, N % 256 == 0.
// 8 waves (2M x 4N), per-wave C = 128x64. BK=64, LDS double-buffered (128 KiB).

#define CFENCE asm volatile("" ::: "memory")
#define VMCNT(n) asm volatile("s_waitcnt vmcnt(" #n ")" ::: "memory")

// stage 64 contiguous rows [rb, rb+64) of a 256x64 tile: 512 threads x 16B
__device__ __forceinline__ void stA64(const u16* __restrict__ g, u16* __restrict__ lds,
                                      int rb, int kb, int lda, int tid){
  int ri = tid >> 3, s = tid & 7;
  int R = rb + ri;                    // rb % 8 == 0 -> R&7 == ri&7
  gl_lds16(g + (size_t)R*lda + kb + ((s ^ (R & 7)) << 3), &lds[(R << 6) + (s << 3)]);
}
// stage two 32-row stripes [rb,rb+32) and [rb+64,rb+96): 512 threads x 16B
__device__ __forceinline__ void stB32x2(const u16* __restrict__ g, u16* __restrict__ lds,
                                        int rb, int kb, int ldb, int tid){
  int ri = tid >> 3, s = tid & 7;
  int R = rb + (ri & 31) + ((ri >> 5) << 6);
  gl_lds16(g + (size_t)R*ldb + kb + ((s ^ (R & 7)) << 3), &lds[(R << 6) + (s << 3)]);
}

#define LDA_Q(QM) \
  _Pragma("unroll") \
  for (int mt=0; mt<4; ++mt){ \
    int row = wm*128 + ((QM)*4+mt)*16 + l16; \
    _Pragma("unroll") \
    for (int kc=0; kc<2; ++kc){ \
      int s = (kc*4+quad) ^ (row & 7); \
      af[mt][kc] = *(const bf16x8*)&sAb[row*64 + s*8]; \
    } \
  }

#define LDB_Q(dst, QN) \
  _Pragma("unroll") \
  for (int nt=0; nt<2; ++nt){ \
    int row = wn*64 + ((QN)*2+nt)*16 + l16; \
    _Pragma("unroll") \
    for (int kc=0; kc<2; ++kc){ \
      int s = (kc*4+quad) ^ (row & 7); \
      dst[nt][kc] = *(const bf16x8*)&sBb[row*64 + s*8]; \
    } \
  }

#define PHASE_MFMA(bfX, QM, QN) \
  __builtin_amdgcn_s_setprio(1); \
  _Pragma("unroll") \
  for (int mt=0; mt<4; ++mt){ \
    _Pragma("unroll") \
    for (int kc=0; kc<2; ++kc){ \
      _Pragma("unroll") \
      for (int nt=0; nt<2; ++nt) \
        acc[(QM)*4+mt][(QN)*2+nt] = __builtin_amdgcn_mfma_f32_16x16x32_bf16( \
            af[mt][kc], bfX[nt][kc], acc[(QM)*4+mt][(QN)*2+nt], 0, 0, 0); \
    } \
  } \
  __builtin_amdgcn_s_setprio(0);

// the shared 8-phase K-loop (operates on Ab/Bb already offset to this block's
// m/n/k origin; NT K-tiles of 64)
#define GEMM256_BODY \
  f32x4 acc[8][4]; \
  _Pragma("unroll") \
  for (int i=0;i<8;i++){ \
    _Pragma("unroll") \
    for (int j=0;j<4;j++) acc[i][j] = zero4(); \
  } \
  stA64 (Ab, sA[0],   0, 0, lda, tid);  stA64 (Ab, sA[0], 128, 0, lda, tid); \
  stB32x2(Bb, sB[0],  0, 0, ldb, tid);  stB32x2(Bb, sB[0], 128, 0, ldb, tid); \
  stA64 (Ab, sA[0],  64, 0, lda, tid);  stA64 (Ab, sA[0], 192, 0, lda, tid); \
  stB32x2(Bb, sB[0], 32, 0, ldb, tid);  stB32x2(Bb, sB[0], 160, 0, ldb, tid); \
  if (NT > 1){ \
    stA64 (Ab, sA[1],   0, 64, lda, tid);  stA64 (Ab, sA[1], 128, 64, lda, tid); \
    stB32x2(Bb, sB[1],  0, 64, ldb, tid);  stB32x2(Bb, sB[1], 128, 64, ldb, tid); \
  } \
  VMCNT(4); \
  CFENCE; __builtin_amdgcn_s_barrier(); CFENCE; \
  bf16x8 af[4][2], bf0[2][2], bf1[2][2]; \
  for (int t = 0; t < NT; ++t){ \
    const int buf = t & 1; \
    const u16* sAb = sA[buf]; \
    const u16* sBb = sB[buf]; \
    u16* sAc = sA[buf]; \
    u16* sBc = sB[buf]; \
    u16* sAn = sA[buf ^ 1]; \
    u16* sBn = sB[buf ^ 1]; \
    const int kb1 = (t+1) << 6; \
    const int kb2 = (t+2) << 6; \
    const bool p1 = (t+1 < NT); \
    const bool p2 = (t+2 < NT); \
    LDA_Q(0) \
    LDB_Q(bf0, 0) \
    if (p1){ stA64(Ab, sAn, 64, kb1, lda, tid); stA64(Ab, sAn, 192, kb1, lda, tid); } \
    CFENCE; __builtin_amdgcn_s_barrier(); CFENCE; \
    PHASE_MFMA(bf0, 0, 0) \
    if (p1){ VMCNT(6); } else { VMCNT(0); } \
    CFENCE; __builtin_amdgcn_s_barrier(); CFENCE; \
    LDB_Q(bf1, 1) \
    if (p1){ stB32x2(Bb, sBn, 32, kb1, ldb, tid); stB32x2(Bb, sBn, 160, kb1, ldb, tid); } \
    CFENCE; __builtin_amdgcn_s_barrier(); CFENCE; \
    PHASE_MFMA(bf1, 0, 1) \
    CFENCE; __builtin_amdgcn_s_barrier(); CFENCE; \
    LDA_Q(1) \
    if (p2){ stA64(Ab, sAc, 0, kb2, lda, tid); stA64(Ab, sAc, 128, kb2, lda, tid); } \
    CFENCE; __builtin_amdgcn_s_barrier(); CFENCE; \
    PHASE_MFMA(bf0, 1, 0) \
    CFENCE; __builtin_amdgcn_s_barrier(); CFENCE; \
    if (p2){ stB32x2(Bb, sBc, 0, kb2, ldb, tid); stB32x2(Bb, sBc, 128, kb2, ldb, tid); } \
    CFENCE; __builtin_amdgcn_s_barrier(); CFENCE; \
    PHASE_MFMA(bf1, 1, 1) \
    if (p2){ VMCNT(8); } else if (p1){ VMCNT(4); } else { VMCNT(0); } \
    CFENCE; __builtin_amdgcn_s_barrier(); CFENCE; \
  }

__global__ void __launch_bounds__(512, 2) gemm256_bias(
    const u16* __restrict__ A, const u16* __restrict__ B, u16* __restrict__ C,
    int K, int lda, int ldb, int ldc, const float* __restrict__ bias)
{
  __shared__ u16 sA[2][256*64];
  __shared__ u16 sB[2][256*64];
  const int tid  = threadIdx.x;
  const int lane = tid & 63;
  const int wv   = tid >> 6;
  const int quad = lane >> 4;
  const int l16  = lane & 15;
  const int wm   = wv >> 2;          // 0..1
  const int wn   = wv & 3;           // 0..3
  const int m0   = blockIdx.x * 256;
  const int n0   = blockIdx.y * 256;
  const u16* Ab  = A + (size_t)m0 * lda;
  const u16* Bb  = B + (size_t)n0 * ldb;
  const int NT   = K >> 6;

  GEMM256_BODY

  // epilogue: bf16 store + bias
  #pragma unroll
  for (int mt=0; mt<8; ++mt){
    #pragma unroll
    for (int nt=0; nt<4; ++nt){
      #pragma unroll
      for (int r=0;r<4;++r){
        int row = m0 + wm*128 + mt*16 + quad*4 + r;
        int col = n0 + wn*64 + nt*16 + l16;
        float v = acc[mt][nt][r] + bias[col];
        C[(size_t)row*ldc + col] = f2bf(v);
      }
    }
  }
}

// split-K variant: blockIdx.z selects K-chunk of KS; partials accumulated
// into pre-zeroed f32 S via hardware global_atomic_add_f32.
__global__ void __launch_bounds__(512, 2) gemm256_splitk(
    const u16* __restrict__ A, const u16* __restrict__ B, float* __restrict__ S,
    int KS, int lda, int ldb, int ldc)
{
  __shared__ u16 sA[2][256*64];
  __shared__ u16 sB[2][256*64];
  const int tid  = threadIdx.x;
  const int lane = tid & 63;
  const int wv   = tid >> 6;
  const int quad = lane >> 4;
  const int l16  = lane & 15;
  const int wm   = wv >> 2;          // 0..1
  const int wn   = wv & 3;           // 0..3
  const int m0   = blockIdx.x * 256;
  const int n0   = blockIdx.y * 256;
  const int kbase = blockIdx.z * KS;
  const u16* Ab  = A + (size_t)m0 * lda + kbase;
  const u16* Bb  = B + (size_t)n0 * ldb + kbase;
  const int NT   = KS >> 6;

  GEMM256_BODY

  // epilogue: atomic f32 accumulate
  #pragma unroll
  for (int mt=0; mt<8; ++mt){
    #pragma unroll
    for (int nt=0; nt<4; ++nt){
      #pragma unroll
      for (int r=0;r<4;++r){
        int row = m0 + wm*128 + mt*16 + quad*4 + r;
        int col = n0 + wn*64 + nt*16 + l16;
        unsafeAtomicAdd(&S[(size_t)row*ldc + col], acc[mt][nt][r]);
      }
    }
  }
}

#undef LDA_Q
#undef LDB_Q
#undef PHASE_MFMA
#undef GEMM256_BODY

// ---------------- flash attention: one block = (head, 64 q-rows) ----------------
// V staging: in-register 4xd transpose from coalesced u64 loads, 4x ds_write_b128
// per thread with swizzle s = kv8 ^ (d&7) ^ ((d>>3)&7) (all 32 banks covered per
// write instruction, 8 lanes / 4-bank group = phased-optimal).
__global__ void __launch_bounds__(256) attn_kernel(
    const u16* __restrict__ qbf, const u16* __restrict__ kbf,
    const u16* __restrict__ h, u16* __restrict__ cat)
{
  __shared__ u16 sQ[64*128];
  __shared__ u16 sK[64*128];
  __shared__ u16 sVT[128*64];
  __shared__ u16 sP[4*16*64];

  const int tid = threadIdx.x;
  const int lane = tid & 63;
  const int wv = tid >> 6;
  const int quad = lane >> 4;
  const int l16 = lane & 15;
  const int l0 = blockIdx.x * 64;
  const int hh = blockIdx.y;

  const u16* qb = qbf + (size_t)hh*SEQ*128;
  const u16* kbp = kbf + (size_t)hh*SEQ*128;

  #pragma unroll
  for (int i=0;i<4;i++){
    int c = i*256 + tid, r = c >> 4, s = c & 15, g = s ^ (r & 15);
    gl_lds16(qb + (size_t)(l0 + r)*128 + g*8, &sQ[c*8]);
  }

  // per-thread V staging geometry (constant across tiles)
  const int kv8 = tid >> 5;            // 0..7 (kv group of 8 rows)
  const int d4  = (tid & 31) * 4;      // 0..124 (4 consecutive d)

  f32x4 accO[8];
  #pragma unroll
  for (int i=0;i<8;i++) accO[i] = zero4();
  float m_i[4] = {-INFINITY,-INFINITY,-INFINITY,-INFINITY};
  float l_i[4] = {0.f,0.f,0.f,0.f};

  for (int kv0 = 0; kv0 < SEQ; kv0 += 64){
    #pragma unroll
    for (int i=0;i<4;i++){
      int c = i*256 + tid, r = c >> 4, s = c & 15, g = s ^ (r & 15);
      gl_lds16(kbp + (size_t)(kv0 + r)*128 + g*8, &sK[c*8]);
    }
    // stage V transposed: 8 coalesced u64 loads (8 kv rows x 4 d), in-register
    // transpose, 4x ds_write_b128
    {
      const u16* src = h + (size_t)(kv0 + kv8*8)*N1 + 6144 + (size_t)hh*128 + d4;
      u64 vv[8];
      #pragma unroll
      for (int j=0;j<8;j++) vv[j] = *(const u64*)(src + (size_t)j*N1);
      #pragma unroll
      for (int jd=0;jd<4;jd++){
        int d = d4 + jd;
        union { u16 u[8]; uint4 q; } t;
        #pragma unroll
        for (int j=0;j<8;j++) t.u[j] = (u16)(vv[j] >> (16*jd));
        int s = kv8 ^ (d & 7) ^ ((d >> 3) & 7);
        *(uint4*)&sVT[d*64 + s*8] = t.q;
      }
    }
    __syncthreads();

    // S = Q K^T (this wave's 16 q-rows x 64 kv)
    f32x4 sacc[4];
    #pragma unroll
    for (int i=0;i<4;i++) sacc[i] = zero4();
    __builtin_amdgcn_s_setprio(1);
    #pragma unroll
    for (int kc=0; kc<4; kc++){
      int arow = wv*16 + l16;
      int as = (kc*4 + quad) ^ (arow & 15);
      bf16x8 aF = *(const bf16x8*)&sQ[arow*128 + as*8];
      #pragma unroll
      for (int nt=0; nt<4; nt++){
        int brow = nt*16 + l16;
        int bs = (kc*4 + quad) ^ (brow & 15);
        bf16x8 bF = *(const bf16x8*)&sK[brow*128 + bs*8];
        sacc[nt] = __builtin_amdgcn_mfma_f32_16x16x32_bf16(aF, bF, sacc[nt], 0, 0, 0);
      }
    }
    __builtin_amdgcn_s_setprio(0);
    const float scl = 0.08838834764831845f;  // 1/sqrt(128)
    #pragma unroll
    for (int nt=0; nt<4; nt++){
      #pragma unroll
      for (int r=0;r<4;r++) sacc[nt][r] *= scl;
    }

    // in-register online softmax (rows live in the 16 lanes of a quad)
    float alpha[4];
    #pragma unroll
    for (int r=0;r<4;r++){
      float v = fmaxf(fmaxf(sacc[0][r],sacc[1][r]), fmaxf(sacc[2][r],sacc[3][r]));
      v = fmaxf(v, __shfl_xor(v,1,64));
      v = fmaxf(v, __shfl_xor(v,2,64));
      v = fmaxf(v, __shfl_xor(v,4,64));
      v = fmaxf(v, __shfl_xor(v,8,64));
      float mnew = fmaxf(m_i[r], v);
      alpha[r] = __expf(m_i[r] - mnew);
      m_i[r] = mnew;
    }
    float p[4][4];
    float rsum[4] = {0.f,0.f,0.f,0.f};
    #pragma unroll
    for (int nt=0; nt<4; nt++){
      #pragma unroll
      for (int r=0;r<4;r++){
        float pv = __expf(sacc[nt][r] - m_i[r]);
        p[nt][r] = pv;
        rsum[r] += pv;
      }
    }
    #pragma unroll
    for (int r=0;r<4;r++){
      float s = rsum[r];
      s += __shfl_xor(s,1,64); s += __shfl_xor(s,2,64);
      s += __shfl_xor(s,4,64); s += __shfl_xor(s,8,64);
      l_i[r] = l_i[r]*alpha[r] + s;
    }
    // write P (C-layout -> A-layout via LDS, per-wave region)
    u16* pw = &sP[wv*1024];
    #pragma unroll
    for (int nt=0; nt<4; nt++){
      #pragma unroll
      for (int r=0;r<4;r++){
        int rloc = quad*4 + r;
        int c = nt*16 + l16;
        int slot = (c >> 3) ^ (rloc & 7);
        pw[rloc*64 + slot*8 + (c & 7)] = f2bf(p[nt][r]);
      }
    }
    // rescale O
    #pragma unroll
    for (int dt=0; dt<8; dt++){
      #pragma unroll
      for (int r=0;r<4;r++) accO[dt][r] *= alpha[r];
    }
    // O += P V
    int prow = l16;
    int ps0 = quad ^ (prow & 7);
    int ps1 = (4 + quad) ^ (prow & 7);
    bf16x8 p0 = *(const bf16x8*)&pw[prow*64 + ps0*8];
    bf16x8 p1 = *(const bf16x8*)&pw[prow*64 + ps1*8];
    __builtin_amdgcn_s_setprio(1);
    #pragma unroll
    for (int dt=0; dt<8; dt++){
      int vrow = dt*16 + l16;
      int hs = (vrow >> 3) & 7;
      int vs0 = (quad ^ (vrow & 7) ^ hs);
      int vs1 = ((4 + quad) ^ (vrow & 7) ^ hs);
      bf16x8 v0 = *(const bf16x8*)&sVT[vrow*64 + vs0*8];
      bf16x8 v1 = *(const bf16x8*)&sVT[vrow*64 + vs1*8];
      accO[dt] = __builtin_amdgcn_mfma_f32_16x16x32_bf16(p0, v0, accO[dt], 0, 0, 0);
      accO[dt] = __builtin_amdgcn_mfma_f32_16x16x32_bf16(p1, v1, accO[dt], 0, 0, 0);
    }
    __builtin_amdgcn_s_setprio(0);
    __syncthreads();
  }

  #pragma unroll
  for (int dt=0; dt<8; dt++){
    #pragma unroll
    for (int r=0;r<4;r++){
      int row = l0 + wv*16 + quad*4 + r;
      int col = hh*128 + dt*16 + l16;
      cat[(size_t)row*CATK + col] = f2bf(accO[dt][r] / l_i[r]);
    }
  }
}

// ---------------- launcher ----------------
extern "C" void kernel_launch(void* const* d_in, const int* in_sizes, int n_in,
                              void* d_out, int out_size, void* d_ws, size_t ws_size,
                              hipStream_t stream)
{
  (void)in_sizes; (void)n_in; (void)out_size; (void)ws_size;
  const float* x    = (const float*)d_in[0];
  const float* vec  = (const float*)d_in[1];
  const float* pe   = (const float*)d_in[2];
  const float* modw = (const float*)d_in[3];
  const float* modb = (const float*)d_in[4];
  const float* w1   = (const float*)d_in[5];
  const float* b1   = (const float*)d_in[6];
  const float* w2   = (const float*)d_in[7];
  const float* b2   = (const float*)d_in[8];
  const float* qs   = (const float*)d_in[9];
  const float* ks   = (const float*)d_in[10];
  const float* lqd  = (const float*)d_in[11];
  const float* lqu  = (const float*)d_in[12];
  const float* lkd  = (const float*)d_in[13];
  const float* lku  = (const float*)d_in[14];
  const float* lvd  = (const float*)d_in[15];
  const float* lvu  = (const float*)d_in[16];
  const float* pd   = (const float*)d_in[17];
  const float* pu   = (const float*)d_in[18];
  float* out = (float*)d_out;

  char* ws = (char*)d_ws;
  float* sv    = (float*)(ws + 0);            // 3072 f32
  float* mvec  = (float*)(ws + 12288);        // 9216 f32
  u16* xm      = (u16*)(ws + 49152);          // 2048 x 3072  (dead after gemm256_bias)
  float* Sacc  = (float*)(ws + 49152);        // 2048 x 3072 f32 (overlays xm/U/DT..., live after gemm256_bias)
  u16* U       = (u16*)(ws + 12632064);       // 9216 x 128
  u16* DT      = (u16*)(ws + 14991360);       // 3072 x 128
  u16* pubf    = (u16*)(ws + 15777792);       // 3072 x 64
  u16* pdT     = (u16*)(ws + 16171008);       // 15360 x 64
  u16* w1ext   = (u16*)(ws + 18137088);       // 21504 x 3072
  u16* w2ext   = (u16*)(ws + 150257664);      // 3072 x 15360
  u16* hbuf    = (u16*)(ws + 244629504);      // 2048 x 21504
  u16* qbf     = (u16*)(ws + 332709888);      // 24 x 2048 x 128
  u16* kbf     = (u16*)(ws + 345292800);      // 24 x 2048 x 128
  u16* cat     = (u16*)(ws + 357875712);      // 2048 x 15360

  // weight prep (lora folded: w1' = w1 + U@Dcat, w2' = w2 + pu@pd)
  cast_w1_tail<<<18432,256,0,stream>>>(w1, w1ext);
  build_ustack<<<576,256,0,stream>>>(lqu,lku,lvu,U);
  build_dcatT<<<192,256,0,stream>>>(lqd,lkd,lvd,DT);
  build_pubf<<<96,256,0,stream>>>(pu,pubf);
  build_pdT<<<480,256,0,stream>>>(pd,pdT);
  // w1ext[0:9216] = bf16(U @ DT^T + w1)     M=9216 N=3072 K=128
  gemm_bt<3><<<dim3(72,24),256,0,stream>>>(U,DT,(void*)w1ext,
      128,128,128,K1,K1,nullptr,w1,nullptr);
  // w2ext = bf16(pubf @ pdT^T + w2)         M=3072 N=15360 K=64
  gemm_bt<3><<<dim3(24,120),256,0,stream>>>(pubf,pdT,(void*)w2ext,
      64,64,64,CATK,CATK,nullptr,w2,nullptr);

  // activations
  silu_kernel<<<12,256,0,stream>>>(vec,sv);
  modgemv_kernel<<<9216,256,0,stream>>>(sv,modw,modb,mvec);
  xmod_kernel<<<2048,256,0,stream>>>(x,mvec,xm);
  // h = x_mod @ w1ext^T + b1                M=2048 N=21504 K=3072  (8-phase 256^2)
  gemm256_bias<<<dim3(8,84),512,0,stream>>>(xm,w1ext,hbuf,K1,K1,K1,N1,b1);
  // zero the split-K accumulator (xm is dead now; Sacc overlays it)
  zero_f32<<<6144,256,0,stream>>>(Sacc);
  qkv_kernel<<<dim3(2048,24),128,0,stream>>>(hbuf,pe,qs,ks,qbf,kbf);
  gelu_kernel<<<dim3(48,2048),256,0,stream>>>(hbuf,cat);
  attn_kernel<<<dim3(32,24),256,0,stream>>>(qbf,kbf,hbuf,cat);
  // S += cat @ w2ext^T  (split-K=8, 768 blocks = 3 full CU waves)
  gemm256_splitk<<<dim3(8,12,8),512,0,stream>>>(cat,w2ext,Sacc,
      CATK/8,CATK,CATK,3072);
  // out = x + gate*(S + b2)
  final_epilogue<<<dim3(2048,3),256,0,stream>>>(Sacc,x,mvec+6144,b2,out);
}

// Round 5
// 1478.432 us; speedup vs baseline: 1.2676x; 1.0125x over previous
//
#include <hip/hip_runtime.h>
#include <math.h>

typedef unsigned short u16;
typedef unsigned int u32;
typedef unsigned long long u64;
typedef __attribute__((ext_vector_type(4))) float f32x4;
typedef __attribute__((ext_vector_type(8))) __bf16 bf16x8;

#define SEQ 2048
#define N1 21504      // 3*HID + MLP
#define K1 3072       // HID
#define CATK 15360    // HID + MLP

__device__ __forceinline__ u16 f2bf(float f){
  u32 u = __float_as_uint(f);
  u32 r = u + 0x7FFFu + ((u >> 16) & 1u);
  return (u16)(r >> 16);
}
__device__ __forceinline__ float bf2f(u16 h){
  return __uint_as_float(((u32)h) << 16);
}
__device__ __forceinline__ void gl_lds16(const void* g, void* l){
  __builtin_amdgcn_global_load_lds(
      (const __attribute__((address_space(1))) void*)(size_t)g,
      (__attribute__((address_space(3))) void*)(u32)(size_t)l, 16, 0, 0);
}
__device__ __forceinline__ f32x4 zero4(){ f32x4 z; z[0]=0.f; z[1]=0.f; z[2]=0.f; z[3]=0.f; return z; }

// ---------------- weight prep kernels ----------------
// cast w1 rows [9216,21504) (the MLP part, no lora) to bf16
__global__ void __launch_bounds__(256) cast_w1_tail(
    const float* __restrict__ w1, u16* __restrict__ out)
{
  int gid = blockIdx.x*256 + threadIdx.x;     // 12288*384
  int n = 9216 + gid / 384;
  int k8 = (gid - (n-9216)*384) * 8;
  const float* src = &w1[(size_t)n*K1 + k8];
  union { u16 u[8]; uint4 q; } t;
  #pragma unroll
  for (int j=0;j<8;j++) t.u[j] = f2bf(src[j]);
  *(uint4*)&out[(size_t)n*K1 + k8] = t.q;
}

// U (9216 x 128 bf16): rows n in block b=n/3072 hold up_b[n%3072][:] in cols [32b,32b+32)
__global__ void __launch_bounds__(256) build_ustack(
    const float* __restrict__ lqu, const float* __restrict__ lku,
    const float* __restrict__ lvu, u16* __restrict__ out)
{
  int gid = blockIdx.x*256 + threadIdx.x;     // 9216*16
  int n = gid >> 4;
  int k8 = (gid & 15) * 8;
  int b = n / 3072;
  const float* up = (b==0)? lqu : (b==1)? lku : lvu;
  int nl = n - b*3072;
  union { u16 u[8]; uint4 q; } t;
  #pragma unroll
  for (int j=0;j<8;j++){
    int r = k8 + j - 32*b;
    t.u[j] = (r >= 0 && r < 32) ? f2bf(up[(size_t)nl*32 + r]) : (u16)0;
  }
  *(uint4*)&out[(size_t)n*128 + k8] = t.q;
}

// DT (3072 x 128 bf16): DT[k][r] = down_{r/32}[r%32][k], zero for r>=96
__global__ void __launch_bounds__(256) build_dcatT(
    const float* __restrict__ lqd, const float* __restrict__ lkd,
    const float* __restrict__ lvd, u16* __restrict__ out)
{
  int gid = blockIdx.x*256 + threadIdx.x;     // 3072*16
  int k = gid >> 4;
  int r8 = (gid & 15) * 8;
  union { u16 u[8]; uint4 q; } t;
  #pragma unroll
  for (int j=0;j<8;j++){
    int r = r8 + j;
    float v = (r < 32) ? lqd[(size_t)r*3072 + k]
            : (r < 64) ? lkd[(size_t)(r-32)*3072 + k]
            : (r < 96) ? lvd[(size_t)(r-64)*3072 + k] : 0.f;
    t.u[j] = f2bf(v);
  }
  *(uint4*)&out[(size_t)k*128 + r8] = t.q;
}

// pu (3072 x 64) -> bf16 cast
__global__ void __launch_bounds__(256) build_pubf(
    const float* __restrict__ pu, u16* __restrict__ out)
{
  int gid = blockIdx.x*256 + threadIdx.x;     // 3072*8
  int n = gid >> 3;
  int r8 = (gid & 7) * 8;
  union { u16 u[8]; uint4 q; } t;
  #pragma unroll
  for (int j=0;j<8;j++) t.u[j] = f2bf(pu[(size_t)n*64 + r8 + j]);
  *(uint4*)&out[(size_t)n*64 + r8] = t.q;
}

// pdT (15360 x 64 bf16): pdT[j][r] = pd[r][j]
__global__ void __launch_bounds__(256) build_pdT(
    const float* __restrict__ pd, u16* __restrict__ out)
{
  int gid = blockIdx.x*256 + threadIdx.x;     // 15360*8
  int jj = gid >> 3;
  int r8 = (gid & 7) * 8;
  union { u16 u[8]; uint4 q; } t;
  #pragma unroll
  for (int j=0;j<8;j++) t.u[j] = f2bf(pd[(size_t)(r8+j)*15360 + jj]);
  *(uint4*)&out[(size_t)jj*64 + r8] = t.q;
}

// ---------------- small vector kernels ----------------
__global__ void __launch_bounds__(256) silu_kernel(const float* __restrict__ v, float* __restrict__ sv){
  int i = blockIdx.x*256 + threadIdx.x;
  float x = v[i];
  sv[i] = x / (1.f + __expf(-x));
}

__global__ void __launch_bounds__(256) modgemv_kernel(
    const float* __restrict__ sv, const float* __restrict__ mw,
    const float* __restrict__ mb, float* __restrict__ mout)
{
  int n = blockIdx.x, tid = threadIdx.x;
  const float* wr = mw + (size_t)n*3072;
  float p = 0.f;
  for (int c = tid; c < 3072; c += 256) p += sv[c]*wr[c];
  #pragma unroll
  for (int o=32;o>0;o>>=1) p += __shfl_down(p,o,64);
  __shared__ float red[4];
  if ((tid & 63)==0) red[tid>>6] = p;
  __syncthreads();
  if (tid==0) mout[n] = red[0]+red[1]+red[2]+red[3] + mb[n];
}

__global__ void __launch_bounds__(256) xmod_kernel(
    const float* __restrict__ x, const float* __restrict__ m, u16* __restrict__ xm)
{
  int l = blockIdx.x, tid = threadIdx.x;
  const float* xr = x + (size_t)l*3072;
  float s1=0.f, s2=0.f;
  for (int c=tid;c<3072;c+=256){ float v = xr[c]; s1+=v; s2+=v*v; }
  #pragma unroll
  for (int o=32;o>0;o>>=1){ s1 += __shfl_down(s1,o,64); s2 += __shfl_down(s2,o,64); }
  __shared__ float r1[4], r2[4];
  if ((tid&63)==0){ r1[tid>>6]=s1; r2[tid>>6]=s2; }
  __syncthreads();
  float su = r1[0]+r1[1]+r1[2]+r1[3];
  float sq = r2[0]+r2[1]+r2[2]+r2[3];
  float mu = su / 3072.f;
  float var = sq/3072.f - mu*mu;
  float rstd = rsqrtf(var + 1e-6f);
  u16* orow = xm + (size_t)l*K1;
  for (int c=tid;c<3072;c+=256){
    float v = (xr[c]-mu)*rstd;
    v = v*(1.f + m[3072+c]) + m[c];
    orow[c] = f2bf(v);
  }
}

__global__ void __launch_bounds__(256) gelu_kernel(const u16* __restrict__ h, u16* __restrict__ cat){
  int j = blockIdx.x*256 + threadIdx.x;  // < 12288
  int l = blockIdx.y;
  float v = bf2f(h[(size_t)l*N1 + 9216 + j]);
  float u = 0.7978845608028654f * (v + 0.044715f*v*v*v);
  float t = 1.f - 2.f/(__expf(2.f*u) + 1.f);   // tanh(u)
  cat[(size_t)l*CATK + 3072 + j] = f2bf(0.5f*v*(1.f + t));
}

__global__ void __launch_bounds__(128) qkv_kernel(
    const u16* __restrict__ h, const float* __restrict__ pe,
    const float* __restrict__ qs, const float* __restrict__ ks,
    u16* __restrict__ qbf, u16* __restrict__ kbf)
{
  const int l = blockIdx.x, hh = blockIdx.y, d = threadIdx.x;
  __shared__ float lq[128], lk[128];
  __shared__ float red[4];
  size_t base = (size_t)l*N1 + (size_t)hh*128 + d;
  float qv = bf2f(h[base]);
  float kv = bf2f(h[base + 3072]);
  float pq = qv*qv, pk = kv*kv;
  #pragma unroll
  for (int o=32;o>0;o>>=1){ pq += __shfl_down(pq,o,64); pk += __shfl_down(pk,o,64); }
  if ((d & 63)==0){ red[(d>>6)*2] = pq; red[(d>>6)*2+1] = pk; }
  __syncthreads();
  float rq = rsqrtf((red[0]+red[2])/128.f + 1e-6f);
  float rk = rsqrtf((red[1]+red[3])/128.f + 1e-6f);
  lq[d] = qv*rq*qs[d];
  lk[d] = kv*rk*ks[d];
  __syncthreads();
  int i = d >> 1;
  const float* peb = pe + ((size_t)l*64 + i)*4 + (size_t)(d&1)*2;
  float qo = peb[0]*lq[2*i] + peb[1]*lq[2*i+1];
  float ko = peb[0]*lk[2*i] + peb[1]*lk[2*i+1];
  size_t ob = ((size_t)hh*SEQ + l)*128 + d;
  qbf[ob] = f2bf(qo);
  kbf[ob] = f2bf(ko);
}

// zero a f32 buffer (count must be grid*256*4)
__global__ void __launch_bounds__(256) zero_f32(float* __restrict__ p){
  ((f32x4*)p)[blockIdx.x*256 + threadIdx.x] = zero4();
}

// out = x + gate[col]*(S + b2[col]) over 2048x3072, f32x4-vectorized
// grid (2048, 3) x 256: row = blockIdx.x, c4 = blockIdx.y*256+tid (768 groups/row)
__global__ void __launch_bounds__(256) final_epilogue(
    const float* __restrict__ S, const float* __restrict__ x,
    const float* __restrict__ gate, const float* __restrict__ b2,
    float* __restrict__ out)
{
  int row = blockIdx.x;
  int c4  = blockIdx.y*256 + threadIdx.x;   // 0..767
  size_t i = (size_t)row*768 + c4;          // f32x4 index
  int col4 = c4 * 4;
  f32x4 s = ((const f32x4*)S)[i];
  f32x4 xv = ((const f32x4*)x)[i];
  f32x4 g = *(const f32x4*)&gate[col4];
  f32x4 b = *(const f32x4*)&b2[col4];
  f32x4 o;
  #pragma unroll
  for (int j=0;j<4;j++) o[j] = xv[j] + g[j]*(s[j] + b[j]);
  ((f32x4*)out)[i] = o;
}

// ---------------- GEMM: C[m,n] = sum_k A[m,k]*B[n,k] (+epilogue) ----------------
// MODE 0: bf16 store, +bias
// MODE 3: bf16 store of (acc + addin_f32[row*ldadd+col])   (weight-fold epilogue)
template<int MODE>
__global__ void __launch_bounds__(256) gemm_bt(
    const u16* __restrict__ A, const u16* __restrict__ B, void* __restrict__ C,
    int K, int lda, int ldb, int ldc, int ldadd,
    const float* __restrict__ bias, const float* __restrict__ xres,
    const float* __restrict__ gate)
{
  __shared__ u16 sA[128*64];
  __shared__ u16 sB[128*64];
  const int tid = threadIdx.x;
  const int lane = tid & 63;
  const int wv = tid >> 6;
  const int quad = lane >> 4;
  const int l16 = lane & 15;
  const int rw = (wv >> 1) * 64;
  const int cw = (wv & 1) * 64;
  const int m0 = blockIdx.x * 128;   // m fastest for B-tile L2 reuse
  const int n0 = blockIdx.y * 128;

  f32x4 acc[4][4];
  #pragma unroll
  for (int i=0;i<4;i++){
    #pragma unroll
    for (int j=0;j<4;j++) acc[i][j] = zero4();
  }

  for (int kb = 0; kb < K; kb += 64){
    #pragma unroll
    for (int i=0;i<4;i++){
      int c = i*256 + tid, r = c >> 3, s = c & 7, g = s ^ (r & 7);
      gl_lds16(A + (size_t)(m0 + r)*lda + kb + g*8, &sA[c*8]);
    }
    #pragma unroll
    for (int i=0;i<4;i++){
      int c = i*256 + tid, r = c >> 3, s = c & 7, g = s ^ (r & 7);
      gl_lds16(B + (size_t)(n0 + r)*ldb + kb + g*8, &sB[c*8]);
    }
    __syncthreads();
    #pragma unroll
    for (int kc=0; kc<2; kc++){
      bf16x8 af[4], bfr[4];
      #pragma unroll
      for (int mt=0; mt<4; mt++){
        int row = rw + mt*16 + l16;
        int s = (kc*4 + quad) ^ (row & 7);
        af[mt] = *(const bf16x8*)&sA[row*64 + s*8];
      }
      #pragma unroll
      for (int nt=0; nt<4; nt++){
        int row = cw + nt*16 + l16;
        int s = (kc*4 + quad) ^ (row & 7);
        bfr[nt] = *(const bf16x8*)&sB[row*64 + s*8];
      }
      #pragma unroll
      for (int mt=0; mt<4; mt++){
        #pragma unroll
        for (int nt=0; nt<4; nt++)
          acc[mt][nt] = __builtin_amdgcn_mfma_f32_16x16x32_bf16(af[mt], bfr[nt], acc[mt][nt], 0, 0, 0);
      }
    }
    __syncthreads();
  }

  #pragma unroll
  for (int mt=0; mt<4; mt++){
    #pragma unroll
    for (int nt=0; nt<4; nt++){
      #pragma unroll
      for (int r=0;r<4;r++){
        int row = m0 + rw + mt*16 + quad*4 + r;
        int col = n0 + cw + nt*16 + l16;
        float v = acc[mt][nt][r];
        if (MODE==0){
          v += bias[col];
          ((u16*)C)[(size_t)row*ldc + col] = f2bf(v);
        } else {
          v += xres[(size_t)row*ldadd + col];
          ((u16*)C)[(size_t)row*ldc + col] = f2bf(v);
        }
      }
    }
  }
}

// ---------------- 256x256 8-phase pipelined GEMM (T1+T2+T3+T4+T5) ----------------
// C[m,n] = sum_k A[m,k]*B[n,k] + bias[n], bf16 out. K % 64 == 0, M % 256 == 0, N % 256 == 0.
// 8 waves (2M x 4N), per-wave C = 128x64. BK=64, LDS double-buffered (128 KiB).

#define CFENCE asm volatile("" ::: "memory")
#define VMCNT(n) asm volatile("s_waitcnt vmcnt(" #n ")" ::: "memory")

// stage 64 contiguous rows [rb, rb+64) of a 256x64 tile: 512 threads x 16B
__device__ __forceinline__ void stA64(const u16* __restrict__ g, u16* __restrict__ lds,
                                      int rb, int kb, int lda, int tid){
  int ri = tid >> 3, s = tid & 7;
  int R = rb + ri;                    // rb % 8 == 0 -> R&7 == ri&7
  gl_lds16(g + (size_t)R*lda + kb + ((s ^ (R & 7)) << 3), &lds[(R << 6) + (s << 3)]);
}
// stage two 32-row stripes [rb,rb+32) and [rb+64,rb+96): 512 threads x 16B
__device__ __forceinline__ void stB32x2(const u16* __restrict__ g, u16* __restrict__ lds,
                                        int rb, int kb, int ldb, int tid){
  int ri = tid >> 3, s = tid & 7;
  int R = rb + (ri & 31) + ((ri >> 5) << 6);
  gl_lds16(g + (size_t)R*ldb + kb + ((s ^ (R & 7)) << 3), &lds[(R << 6) + (s << 3)]);
}

#define LDA_Q(QM) \
  _Pragma("unroll") \
  for (int mt=0; mt<4; ++mt){ \
    int row = wm*128 + ((QM)*4+mt)*16 + l16; \
    _Pragma("unroll") \
    for (int kc=0; kc<2; ++kc){ \
      int s = (kc*4+quad) ^ (row & 7); \
      af[mt][kc] = *(const bf16x8*)&sAb[row*64 + s*8]; \
    } \
  }

#define LDB_Q(dst, QN) \
  _Pragma("unroll") \
  for (int nt=0; nt<2; ++nt){ \
    int row = wn*64 + ((QN)*2+nt)*16 + l16; \
    _Pragma("unroll") \
    for (int kc=0; kc<2; ++kc){ \
      int s = (kc*4+quad) ^ (row & 7); \
      dst[nt][kc] = *(const bf16x8*)&sBb[row*64 + s*8]; \
    } \
  }

#define PHASE_MFMA(bfX, QM, QN) \
  __builtin_amdgcn_s_setprio(1); \
  _Pragma("unroll") \
  for (int mt=0; mt<4; ++mt){ \
    _Pragma("unroll") \
    for (int kc=0; kc<2; ++kc){ \
      _Pragma("unroll") \
      for (int nt=0; nt<2; ++nt) \
        acc[(QM)*4+mt][(QN)*2+nt] = __builtin_amdgcn_mfma_f32_16x16x32_bf16( \
            af[mt][kc], bfX[nt][kc], acc[(QM)*4+mt][(QN)*2+nt], 0, 0, 0); \
    } \
  } \
  __builtin_amdgcn_s_setprio(0);

// the shared 8-phase K-loop (operates on Ab/Bb already offset to this block's
// m/n/k origin; NT K-tiles of 64)
#define GEMM256_BODY \
  f32x4 acc[8][4]; \
  _Pragma("unroll") \
  for (int i=0;i<8;i++){ \
    _Pragma("unroll") \
    for (int j=0;j<4;j++) acc[i][j] = zero4(); \
  } \
  stA64 (Ab, sA[0],   0, 0, lda, tid);  stA64 (Ab, sA[0], 128, 0, lda, tid); \
  stB32x2(Bb, sB[0],  0, 0, ldb, tid);  stB32x2(Bb, sB[0], 128, 0, ldb, tid); \
  stA64 (Ab, sA[0],  64, 0, lda, tid);  stA64 (Ab, sA[0], 192, 0, lda, tid); \
  stB32x2(Bb, sB[0], 32, 0, ldb, tid);  stB32x2(Bb, sB[0], 160, 0, ldb, tid); \
  if (NT > 1){ \
    stA64 (Ab, sA[1],   0, 64, lda, tid);  stA64 (Ab, sA[1], 128, 64, lda, tid); \
    stB32x2(Bb, sB[1],  0, 64, ldb, tid);  stB32x2(Bb, sB[1], 128, 64, ldb, tid); \
  } \
  VMCNT(4); \
  CFENCE; __builtin_amdgcn_s_barrier(); CFENCE; \
  bf16x8 af[4][2], bf0[2][2], bf1[2][2]; \
  for (int t = 0; t < NT; ++t){ \
    const int buf = t & 1; \
    const u16* sAb = sA[buf]; \
    const u16* sBb = sB[buf]; \
    u16* sAc = sA[buf]; \
    u16* sBc = sB[buf]; \
    u16* sAn = sA[buf ^ 1]; \
    u16* sBn = sB[buf ^ 1]; \
    const int kb1 = (t+1) << 6; \
    const int kb2 = (t+2) << 6; \
    const bool p1 = (t+1 < NT); \
    const bool p2 = (t+2 < NT); \
    LDA_Q(0) \
    LDB_Q(bf0, 0) \
    if (p1){ stA64(Ab, sAn, 64, kb1, lda, tid); stA64(Ab, sAn, 192, kb1, lda, tid); } \
    CFENCE; __builtin_amdgcn_s_barrier(); CFENCE; \
    PHASE_MFMA(bf0, 0, 0) \
    if (p1){ VMCNT(6); } else { VMCNT(0); } \
    CFENCE; __builtin_amdgcn_s_barrier(); CFENCE; \
    LDB_Q(bf1, 1) \
    if (p1){ stB32x2(Bb, sBn, 32, kb1, ldb, tid); stB32x2(Bb, sBn, 160, kb1, ldb, tid); } \
    CFENCE; __builtin_amdgcn_s_barrier(); CFENCE; \
    PHASE_MFMA(bf1, 0, 1) \
    CFENCE; __builtin_amdgcn_s_barrier(); CFENCE; \
    LDA_Q(1) \
    if (p2){ stA64(Ab, sAc, 0, kb2, lda, tid); stA64(Ab, sAc, 128, kb2, lda, tid); } \
    CFENCE; __builtin_amdgcn_s_barrier(); CFENCE; \
    PHASE_MFMA(bf0, 1, 0) \
    CFENCE; __builtin_amdgcn_s_barrier(); CFENCE; \
    if (p2){ stB32x2(Bb, sBc, 0, kb2, ldb, tid); stB32x2(Bb, sBc, 128, kb2, ldb, tid); } \
    CFENCE; __builtin_amdgcn_s_barrier(); CFENCE; \
    PHASE_MFMA(bf1, 1, 1) \
    if (p2){ VMCNT(8); } else if (p1){ VMCNT(4); } else { VMCNT(0); } \
    CFENCE; __builtin_amdgcn_s_barrier(); CFENCE; \
  }

// flat grid 672 = 8 XCDs x 84; bijective swizzle: XCD k gets nid [84k,84k+84),
// m fastest -> 8 concurrent same-XCD blocks share one B-panel (L2-resident).
__global__ void __launch_bounds__(512, 2) gemm256_bias(
    const u16* __restrict__ A, const u16* __restrict__ B, u16* __restrict__ C,
    int K, int lda, int ldb, int ldc, const float* __restrict__ bias)
{
  __shared__ u16 sA[2][256*64];
  __shared__ u16 sB[2][256*64];
  const int tid  = threadIdx.x;
  const int lane = tid & 63;
  const int wv   = tid >> 6;
  const int quad = lane >> 4;
  const int l16  = lane & 15;
  const int wm   = wv >> 2;          // 0..1
  const int wn   = wv & 3;           // 0..3
  const int lin  = blockIdx.x;       // 0..671
  const int nid  = (lin & 7)*84 + (lin >> 3);
  const int m0   = (nid & 7) * 256;
  const int n0   = (nid >> 3) * 256;
  const u16* Ab  = A + (size_t)m0 * lda;
  const u16* Bb  = B + (size_t)n0 * ldb;
  const int NT   = K >> 6;

  GEMM256_BODY

  // epilogue: bf16 store + bias
  #pragma unroll
  for (int mt=0; mt<8; ++mt){
    #pragma unroll
    for (int nt=0; nt<4; ++nt){
      #pragma unroll
      for (int r=0;r<4;++r){
        int row = m0 + wm*128 + mt*16 + quad*4 + r;
        int col = n0 + wn*64 + nt*16 + l16;
        float v = acc[mt][nt][r] + bias[col];
        C[(size_t)row*ldc + col] = f2bf(v);
      }
    }
  }
}

// split-K variant, flat grid 768 = 8 XCDs x 96: z = lin&7 (each XCD owns one
// K-chunk -> its ~20 MB operand chunk streams through its own L2); within-XCD
// tile order m-fastest, staggered by z*12 so XCDs don't collide on the same
// output tile's atomics. Partials accumulated via hardware global_atomic_add_f32.
__global__ void __launch_bounds__(512, 2) gemm256_splitk(
    const u16* __restrict__ A, const u16* __restrict__ B, float* __restrict__ S,
    int KS, int lda, int ldb, int ldc)
{
  __shared__ u16 sA[2][256*64];
  __shared__ u16 sB[2][256*64];
  const int tid  = threadIdx.x;
  const int lane = tid & 63;
  const int wv   = tid >> 6;
  const int quad = lane >> 4;
  const int l16  = lane & 15;
  const int wm   = wv >> 2;          // 0..1
  const int wn   = wv & 3;           // 0..3
  const int lin  = blockIdx.x;       // 0..767
  const int z    = lin & 7;
  int idx = (lin >> 3) + z*12;
  idx = (idx >= 96) ? idx - 96 : idx;   // stagger, bijective
  const int m0   = (idx & 7) * 256;
  const int n0   = (idx >> 3) * 256;
  const int kbase = z * KS;
  const u16* Ab  = A + (size_t)m0 * lda + kbase;
  const u16* Bb  = B + (size_t)n0 * ldb + kbase;
  const int NT   = KS >> 6;

  GEMM256_BODY

  // epilogue: atomic f32 accumulate
  #pragma unroll
  for (int mt=0; mt<8; ++mt){
    #pragma unroll
    for (int nt=0; nt<4; ++nt){
      #pragma unroll
      for (int r=0;r<4;++r){
        int row = m0 + wm*128 + mt*16 + quad*4 + r;
        int col = n0 + wn*64 + nt*16 + l16;
        unsafeAtomicAdd(&S[(size_t)row*ldc + col], acc[mt][nt][r]);
      }
    }
  }
}

#undef LDA_Q
#undef LDB_Q
#undef PHASE_MFMA
#undef GEMM256_BODY

// ---------------- flash attention: one block = (head, 64 q-rows) ----------------
// flat grid 768 = 8 XCDs x 96: XCD k serves heads [3k,3k+3) -> per-head K/V
// becomes L2-resident on exactly one XCD.
// V staging: in-register 4xd transpose from coalesced u64 loads, 4x ds_write_b128
// per thread with swizzle s = kv8 ^ (d&7) ^ ((d>>3)&7).
__global__ void __launch_bounds__(256) attn_kernel(
    const u16* __restrict__ qbf, const u16* __restrict__ kbf,
    const u16* __restrict__ h, u16* __restrict__ cat)
{
  __shared__ u16 sQ[64*128];
  __shared__ u16 sK[64*128];
  __shared__ u16 sVT[128*64];
  __shared__ u16 sP[4*16*64];

  const int tid = threadIdx.x;
  const int lane = tid & 63;
  const int wv = tid >> 6;
  const int quad = lane >> 4;
  const int l16 = lane & 15;
  const int lin = blockIdx.x;          // 0..767
  const int nid = (lin & 7)*96 + (lin >> 3);
  const int l0 = (nid & 31) * 64;
  const int hh = nid >> 5;

  const u16* qb = qbf + (size_t)hh*SEQ*128;
  const u16* kbp = kbf + (size_t)hh*SEQ*128;

  #pragma unroll
  for (int i=0;i<4;i++){
    int c = i*256 + tid, r = c >> 4, s = c & 15, g = s ^ (r & 15);
    gl_lds16(qb + (size_t)(l0 + r)*128 + g*8, &sQ[c*8]);
  }

  // per-thread V staging geometry (constant across tiles)
  const int kv8 = tid >> 5;            // 0..7 (kv group of 8 rows)
  const int d4  = (tid & 31) * 4;      // 0..124 (4 consecutive d)

  f32x4 accO[8];
  #pragma unroll
  for (int i=0;i<8;i++) accO[i] = zero4();
  float m_i[4] = {-INFINITY,-INFINITY,-INFINITY,-INFINITY};
  float l_i[4] = {0.f,0.f,0.f,0.f};

  for (int kv0 = 0; kv0 < SEQ; kv0 += 64){
    #pragma unroll
    for (int i=0;i<4;i++){
      int c = i*256 + tid, r = c >> 4, s = c & 15, g = s ^ (r & 15);
      gl_lds16(kbp + (size_t)(kv0 + r)*128 + g*8, &sK[c*8]);
    }
    // stage V transposed: 8 coalesced u64 loads (8 kv rows x 4 d), in-register
    // transpose, 4x ds_write_b128
    {
      const u16* src = h + (size_t)(kv0 + kv8*8)*N1 + 6144 + (size_t)hh*128 + d4;
      u64 vv[8];
      #pragma unroll
      for (int j=0;j<8;j++) vv[j] = *(const u64*)(src + (size_t)j*N1);
      #pragma unroll
      for (int jd=0;jd<4;jd++){
        int d = d4 + jd;
        union { u16 u[8]; uint4 q; } t;
        #pragma unroll
        for (int j=0;j<8;j++) t.u[j] = (u16)(vv[j] >> (16*jd));
        int s = kv8 ^ (d & 7) ^ ((d >> 3) & 7);
        *(uint4*)&sVT[d*64 + s*8] = t.q;
      }
    }
    __syncthreads();

    // S = Q K^T (this wave's 16 q-rows x 64 kv)
    f32x4 sacc[4];
    #pragma unroll
    for (int i=0;i<4;i++) sacc[i] = zero4();
    __builtin_amdgcn_s_setprio(1);
    #pragma unroll
    for (int kc=0; kc<4; kc++){
      int arow = wv*16 + l16;
      int as = (kc*4 + quad) ^ (arow & 15);
      bf16x8 aF = *(const bf16x8*)&sQ[arow*128 + as*8];
      #pragma unroll
      for (int nt=0; nt<4; nt++){
        int brow = nt*16 + l16;
        int bs = (kc*4 + quad) ^ (brow & 15);
        bf16x8 bF = *(const bf16x8*)&sK[brow*128 + bs*8];
        sacc[nt] = __builtin_amdgcn_mfma_f32_16x16x32_bf16(aF, bF, sacc[nt], 0, 0, 0);
      }
    }
    __builtin_amdgcn_s_setprio(0);
    const float scl = 0.08838834764831845f;  // 1/sqrt(128)
    #pragma unroll
    for (int nt=0; nt<4; nt++){
      #pragma unroll
      for (int r=0;r<4;r++) sacc[nt][r] *= scl;
    }

    // in-register online softmax (rows live in the 16 lanes of a quad)
    float alpha[4];
    #pragma unroll
    for (int r=0;r<4;r++){
      float v = fmaxf(fmaxf(sacc[0][r],sacc[1][r]), fmaxf(sacc[2][r],sacc[3][r]));
      v = fmaxf(v, __shfl_xor(v,1,64));
      v = fmaxf(v, __shfl_xor(v,2,64));
      v = fmaxf(v, __shfl_xor(v,4,64));
      v = fmaxf(v, __shfl_xor(v,8,64));
      float mnew = fmaxf(m_i[r], v);
      alpha[r] = __expf(m_i[r] - mnew);
      m_i[r] = mnew;
    }
    float p[4][4];
    float rsum[4] = {0.f,0.f,0.f,0.f};
    #pragma unroll
    for (int nt=0; nt<4; nt++){
      #pragma unroll
      for (int r=0;r<4;r++){
        float pv = __expf(sacc[nt][r] - m_i[r]);
        p[nt][r] = pv;
        rsum[r] += pv;
      }
    }
    #pragma unroll
    for (int r=0;r<4;r++){
      float s = rsum[r];
      s += __shfl_xor(s,1,64); s += __shfl_xor(s,2,64);
      s += __shfl_xor(s,4,64); s += __shfl_xor(s,8,64);
      l_i[r] = l_i[r]*alpha[r] + s;
    }
    // write P (C-layout -> A-layout via LDS, per-wave region)
    u16* pw = &sP[wv*1024];
    #pragma unroll
    for (int nt=0; nt<4; nt++){
      #pragma unroll
      for (int r=0;r<4;r++){
        int rloc = quad*4 + r;
        int c = nt*16 + l16;
        int slot = (c >> 3) ^ (rloc & 7);
        pw[rloc*64 + slot*8 + (c & 7)] = f2bf(p[nt][r]);
      }
    }
    // rescale O
    #pragma unroll
    for (int dt=0; dt<8; dt++){
      #pragma unroll
      for (int r=0;r<4;r++) accO[dt][r] *= alpha[r];
    }
    // O += P V
    int prow = l16;
    int ps0 = quad ^ (prow & 7);
    int ps1 = (4 + quad) ^ (prow & 7);
    bf16x8 p0 = *(const bf16x8*)&pw[prow*64 + ps0*8];
    bf16x8 p1 = *(const bf16x8*)&pw[prow*64 + ps1*8];
    __builtin_amdgcn_s_setprio(1);
    #pragma unroll
    for (int dt=0; dt<8; dt++){
      int vrow = dt*16 + l16;
      int hs = (vrow >> 3) & 7;
      int vs0 = (quad ^ (vrow & 7) ^ hs);
      int vs1 = ((4 + quad) ^ (vrow & 7) ^ hs);
      bf16x8 v0 = *(const bf16x8*)&sVT[vrow*64 + vs0*8];
      bf16x8 v1 = *(const bf16x8*)&sVT[vrow*64 + vs1*8];
      accO[dt] = __builtin_amdgcn_mfma_f32_16x16x32_bf16(p0, v0, accO[dt], 0, 0, 0);
      accO[dt] = __builtin_amdgcn_mfma_f32_16x16x32_bf16(p1, v1, accO[dt], 0, 0, 0);
    }
    __builtin_amdgcn_s_setprio(0);
    __syncthreads();
  }

  #pragma unroll
  for (int dt=0; dt<8; dt++){
    #pragma unroll
    for (int r=0;r<4;r++){
      int row = l0 + wv*16 + quad*4 + r;
      int col = hh*128 + dt*16 + l16;
      cat[(size_t)row*CATK + col] = f2bf(accO[dt][r] / l_i[r]);
    }
  }
}

// ---------------- launcher ----------------
extern "C" void kernel_launch(void* const* d_in, const int* in_sizes, int n_in,
                              void* d_out, int out_size, void* d_ws, size_t ws_size,
                              hipStream_t stream)
{
  (void)in_sizes; (void)n_in; (void)out_size; (void)ws_size;
  const float* x    = (const float*)d_in[0];
  const float* vec  = (const float*)d_in[1];
  const float* pe   = (const float*)d_in[2];
  const float* modw = (const float*)d_in[3];
  const float* modb = (const float*)d_in[4];
  const float* w1   = (const float*)d_in[5];
  const float* b1   = (const float*)d_in[6];
  const float* w2   = (const float*)d_in[7];
  const float* b2   = (const float*)d_in[8];
  const float* qs   = (const float*)d_in[9];
  const float* ks   = (const float*)d_in[10];
  const float* lqd  = (const float*)d_in[11];
  const float* lqu  = (const float*)d_in[12];
  const float* lkd  = (const float*)d_in[13];
  const float* lku  = (const float*)d_in[14];
  const float* lvd  = (const float*)d_in[15];
  const float* lvu  = (const float*)d_in[16];
  const float* pd   = (const float*)d_in[17];
  const float* pu   = (const float*)d_in[18];
  float* out = (float*)d_out;

  char* ws = (char*)d_ws;
  float* sv    = (float*)(ws + 0);            // 3072 f32
  float* mvec  = (float*)(ws + 12288);        // 9216 f32
  u16* xm      = (u16*)(ws + 49152);          // 2048 x 3072  (dead after gemm256_bias)
  float* Sacc  = (float*)(ws + 49152);        // 2048 x 3072 f32 (overlays xm/U/DT..., live after gemm256_bias)
  u16* U       = (u16*)(ws + 12632064);       // 9216 x 128
  u16* DT      = (u16*)(ws + 14991360);       // 3072 x 128
  u16* pubf    = (u16*)(ws + 15777792);       // 3072 x 64
  u16* pdT     = (u16*)(ws + 16171008);       // 15360 x 64
  u16* w1ext   = (u16*)(ws + 18137088);       // 21504 x 3072
  u16* w2ext   = (u16*)(ws + 150257664);      // 3072 x 15360
  u16* hbuf    = (u16*)(ws + 244629504);      // 2048 x 21504
  u16* qbf     = (u16*)(ws + 332709888);      // 24 x 2048 x 128
  u16* kbf     = (u16*)(ws + 345292800);      // 24 x 2048 x 128
  u16* cat     = (u16*)(ws + 357875712);      // 2048 x 15360

  // weight prep (lora folded: w1' = w1 + U@Dcat, w2' = w2 + pu@pd)
  cast_w1_tail<<<18432,256,0,stream>>>(w1, w1ext);
  build_ustack<<<576,256,0,stream>>>(lqu,lku,lvu,U);
  build_dcatT<<<192,256,0,stream>>>(lqd,lkd,lvd,DT);
  build_pubf<<<96,256,0,stream>>>(pu,pubf);
  build_pdT<<<480,256,0,stream>>>(pd,pdT);
  // w1ext[0:9216] = bf16(U @ DT^T + w1)     M=9216 N=3072 K=128
  gemm_bt<3><<<dim3(72,24),256,0,stream>>>(U,DT,(void*)w1ext,
      128,128,128,K1,K1,nullptr,w1,nullptr);
  // w2ext = bf16(pubf @ pdT^T + w2)         M=3072 N=15360 K=64
  gemm_bt<3><<<dim3(24,120),256,0,stream>>>(pubf,pdT,(void*)w2ext,
      64,64,64,CATK,CATK,nullptr,w2,nullptr);

  // activations
  silu_kernel<<<12,256,0,stream>>>(vec,sv);
  modgemv_kernel<<<9216,256,0,stream>>>(sv,modw,modb,mvec);
  xmod_kernel<<<2048,256,0,stream>>>(x,mvec,xm);
  // h = x_mod @ w1ext^T + b1                M=2048 N=21504 K=3072  (8-phase 256^2, XCD-swizzled)
  gemm256_bias<<<672,512,0,stream>>>(xm,w1ext,hbuf,K1,K1,K1,N1,b1);
  // zero the split-K accumulator (xm is dead now; Sacc overlays it)
  zero_f32<<<6144,256,0,stream>>>(Sacc);
  qkv_kernel<<<dim3(2048,24),128,0,stream>>>(hbuf,pe,qs,ks,qbf,kbf);
  gelu_kernel<<<dim3(48,2048),256,0,stream>>>(hbuf,cat);
  attn_kernel<<<768,256,0,stream>>>(qbf,kbf,hbuf,cat);
  // S += cat @ w2ext^T  (split-K=8, XCD-swizzled: one K-chunk per XCD)
  gemm256_splitk<<<768,512,0,stream>>>(cat,w2ext,Sacc,
      CATK/8,CATK,CATK,3072);
  // out = x + gate*(S + b2)
  final_epilogue<<<dim3(2048,3),256,0,stream>>>(Sacc,x,mvec+6144,b2,out);
}

// Round 6
// 1346.359 us; speedup vs baseline: 1.3920x; 1.0981x over previous
//
#include <hip/hip_runtime.h>
#include <math.h>

typedef unsigned short u16;
typedef unsigned int u32;
typedef unsigned long long u64;
typedef __attribute__((ext_vector_type(4))) float f32x4;
typedef __attribute__((ext_vector_type(8))) __bf16 bf16x8;

#define SEQ 2048
#define N1 21504      // 3*HID + MLP
#define K1 3072       // HID
#define CATK 15360    // HID + MLP
#define SPLITK 8
#define SPN (2048*3072)   // elements per split-K partial

__device__ __forceinline__ u16 f2bf(float f){
  u32 u = __float_as_uint(f);
  u32 r = u + 0x7FFFu + ((u >> 16) & 1u);
  return (u16)(r >> 16);
}
__device__ __forceinline__ float bf2f(u16 h){
  return __uint_as_float(((u32)h) << 16);
}
__device__ __forceinline__ void gl_lds16(const void* g, void* l){
  __builtin_amdgcn_global_load_lds(
      (const __attribute__((address_space(1))) void*)(size_t)g,
      (__attribute__((address_space(3))) void*)(u32)(size_t)l, 16, 0, 0);
}
__device__ __forceinline__ f32x4 zero4(){ f32x4 z; z[0]=0.f; z[1]=0.f; z[2]=0.f; z[3]=0.f; return z; }

// ---------------- weight prep kernels ----------------
// cast w1 rows [9216,21504) (the MLP part, no lora) to bf16
__global__ void __launch_bounds__(256) cast_w1_tail(
    const float* __restrict__ w1, u16* __restrict__ out)
{
  int gid = blockIdx.x*256 + threadIdx.x;     // 12288*384
  int n = 9216 + gid / 384;
  int k8 = (gid - (n-9216)*384) * 8;
  const float* src = &w1[(size_t)n*K1 + k8];
  union { u16 u[8]; uint4 q; } t;
  #pragma unroll
  for (int j=0;j<8;j++) t.u[j] = f2bf(src[j]);
  *(uint4*)&out[(size_t)n*K1 + k8] = t.q;
}

// U (9216 x 128 bf16): rows n in block b=n/3072 hold up_b[n%3072][:] in cols [32b,32b+32)
__global__ void __launch_bounds__(256) build_ustack(
    const float* __restrict__ lqu, const float* __restrict__ lku,
    const float* __restrict__ lvu, u16* __restrict__ out)
{
  int gid = blockIdx.x*256 + threadIdx.x;     // 9216*16
  int n = gid >> 4;
  int k8 = (gid & 15) * 8;
  int b = n / 3072;
  const float* up = (b==0)? lqu : (b==1)? lku : lvu;
  int nl = n - b*3072;
  union { u16 u[8]; uint4 q; } t;
  #pragma unroll
  for (int j=0;j<8;j++){
    int r = k8 + j - 32*b;
    t.u[j] = (r >= 0 && r < 32) ? f2bf(up[(size_t)nl*32 + r]) : (u16)0;
  }
  *(uint4*)&out[(size_t)n*128 + k8] = t.q;
}

// DT (3072 x 128 bf16): DT[k][r] = down_{r/32}[r%32][k], zero for r>=96
__global__ void __launch_bounds__(256) build_dcatT(
    const float* __restrict__ lqd, const float* __restrict__ lkd,
    const float* __restrict__ lvd, u16* __restrict__ out)
{
  int gid = blockIdx.x*256 + threadIdx.x;     // 3072*16
  int k = gid >> 4;
  int r8 = (gid & 15) * 8;
  union { u16 u[8]; uint4 q; } t;
  #pragma unroll
  for (int j=0;j<8;j++){
    int r = r8 + j;
    float v = (r < 32) ? lqd[(size_t)r*3072 + k]
            : (r < 64) ? lkd[(size_t)(r-32)*3072 + k]
            : (r < 96) ? lvd[(size_t)(r-64)*3072 + k] : 0.f;
    t.u[j] = f2bf(v);
  }
  *(uint4*)&out[(size_t)k*128 + r8] = t.q;
}

// pu (3072 x 64) -> bf16 cast
__global__ void __launch_bounds__(256) build_pubf(
    const float* __restrict__ pu, u16* __restrict__ out)
{
  int gid = blockIdx.x*256 + threadIdx.x;     // 3072*8
  int n = gid >> 3;
  int r8 = (gid & 7) * 8;
  union { u16 u[8]; uint4 q; } t;
  #pragma unroll
  for (int j=0;j<8;j++) t.u[j] = f2bf(pu[(size_t)n*64 + r8 + j]);
  *(uint4*)&out[(size_t)n*64 + r8] = t.q;
}

// pdT (15360 x 64 bf16): pdT[j][r] = pd[r][j]
__global__ void __launch_bounds__(256) build_pdT(
    const float* __restrict__ pd, u16* __restrict__ out)
{
  int gid = blockIdx.x*256 + threadIdx.x;     // 15360*8
  int jj = gid >> 3;
  int r8 = (gid & 7) * 8;
  union { u16 u[8]; uint4 q; } t;
  #pragma unroll
  for (int j=0;j<8;j++) t.u[j] = f2bf(pd[(size_t)(r8+j)*15360 + jj]);
  *(uint4*)&out[(size_t)jj*64 + r8] = t.q;
}

// ---------------- small vector kernels ----------------
// modgemv with silu fused: m[n] = sum_c silu(vec[c])*mw[n,c] + mb[n]
__global__ void __launch_bounds__(256) modgemv_kernel(
    const float* __restrict__ vec, const float* __restrict__ mw,
    const float* __restrict__ mb, float* __restrict__ mout)
{
  int n = blockIdx.x, tid = threadIdx.x;
  const float* wr = mw + (size_t)n*3072;
  float p = 0.f;
  for (int c = tid; c < 3072; c += 256){
    float xv = vec[c];
    p += (xv / (1.f + __expf(-xv))) * wr[c];
  }
  #pragma unroll
  for (int o=32;o>0;o>>=1) p += __shfl_down(p,o,64);
  __shared__ float red[4];
  if ((tid & 63)==0) red[tid>>6] = p;
  __syncthreads();
  if (tid==0) mout[n] = red[0]+red[1]+red[2]+red[3] + mb[n];
}

__global__ void __launch_bounds__(256) xmod_kernel(
    const float* __restrict__ x, const float* __restrict__ m, u16* __restrict__ xm)
{
  int l = blockIdx.x, tid = threadIdx.x;
  const float* xr = x + (size_t)l*3072;
  float s1=0.f, s2=0.f;
  for (int c=tid;c<3072;c+=256){ float v = xr[c]; s1+=v; s2+=v*v; }
  #pragma unroll
  for (int o=32;o>0;o>>=1){ s1 += __shfl_down(s1,o,64); s2 += __shfl_down(s2,o,64); }
  __shared__ float r1[4], r2[4];
  if ((tid&63)==0){ r1[tid>>6]=s1; r2[tid>>6]=s2; }
  __syncthreads();
  float su = r1[0]+r1[1]+r1[2]+r1[3];
  float sq = r2[0]+r2[1]+r2[2]+r2[3];
  float mu = su / 3072.f;
  float var = sq/3072.f - mu*mu;
  float rstd = rsqrtf(var + 1e-6f);
  u16* orow = xm + (size_t)l*K1;
  for (int c=tid;c<3072;c+=256){
    float v = (xr[c]-mu)*rstd;
    v = v*(1.f + m[3072+c]) + m[c];
    orow[c] = f2bf(v);
  }
}

__global__ void __launch_bounds__(128) qkv_kernel(
    const u16* __restrict__ h, const float* __restrict__ pe,
    const float* __restrict__ qs, const float* __restrict__ ks,
    u16* __restrict__ qbf, u16* __restrict__ kbf)
{
  const int l = blockIdx.x, hh = blockIdx.y, d = threadIdx.x;
  __shared__ float lq[128], lk[128];
  __shared__ float red[4];
  size_t base = (size_t)l*N1 + (size_t)hh*128 + d;
  float qv = bf2f(h[base]);
  float kv = bf2f(h[base + 3072]);
  float pq = qv*qv, pk = kv*kv;
  #pragma unroll
  for (int o=32;o>0;o>>=1){ pq += __shfl_down(pq,o,64); pk += __shfl_down(pk,o,64); }
  if ((d & 63)==0){ red[(d>>6)*2] = pq; red[(d>>6)*2+1] = pk; }
  __syncthreads();
  float rq = rsqrtf((red[0]+red[2])/128.f + 1e-6f);
  float rk = rsqrtf((red[1]+red[3])/128.f + 1e-6f);
  lq[d] = qv*rq*qs[d];
  lk[d] = kv*rk*ks[d];
  __syncthreads();
  int i = d >> 1;
  const float* peb = pe + ((size_t)l*64 + i)*4 + (size_t)(d&1)*2;
  float qo = peb[0]*lq[2*i] + peb[1]*lq[2*i+1];
  float ko = peb[0]*lk[2*i] + peb[1]*lk[2*i+1];
  size_t ob = ((size_t)hh*SEQ + l)*128 + d;
  qbf[ob] = f2bf(qo);
  kbf[ob] = f2bf(ko);
}

// out = x + gate[col]*(sum_z SP[z] + b2[col]) over 2048x3072
// grid (2048, 3) x 256: row = blockIdx.x, c4 = blockIdx.y*256+tid (768 groups/row)
__global__ void __launch_bounds__(256) final_epilogue(
    const u16* __restrict__ SP, const float* __restrict__ x,
    const float* __restrict__ gate, const float* __restrict__ b2,
    float* __restrict__ out)
{
  int row = blockIdx.x;
  int c4  = blockIdx.y*256 + threadIdx.x;   // 0..767
  size_t base = (size_t)row*3072 + c4*4;
  int col4 = c4 * 4;
  f32x4 s = zero4();
  #pragma unroll
  for (int z=0; z<SPLITK; z++){
    u64 v = *(const u64*)&SP[(size_t)z*SPN + base];
    s[0] += bf2f((u16)v);
    s[1] += bf2f((u16)(v >> 16));
    s[2] += bf2f((u16)(v >> 32));
    s[3] += bf2f((u16)(v >> 48));
  }
  f32x4 xv = *(const f32x4*)&x[base];
  f32x4 g = *(const f32x4*)&gate[col4];
  f32x4 b = *(const f32x4*)&b2[col4];
  f32x4 o;
  #pragma unroll
  for (int j=0;j<4;j++) o[j] = xv[j] + g[j]*(s[j] + b[j]);
  *(f32x4*)&out[base] = o;
}

// ---------------- GEMM: C[m,n] = sum_k A[m,k]*B[n,k] (+epilogue) ----------------
// MODE 0: bf16 store, +bias
// MODE 3: bf16 store of (acc + addin_f32[row*ldadd+col])   (weight-fold epilogue)
template<int MODE>
__global__ void __launch_bounds__(256) gemm_bt(
    const u16* __restrict__ A, const u16* __restrict__ B, void* __restrict__ C,
    int K, int lda, int ldb, int ldc, int ldadd,
    const float* __restrict__ bias, const float* __restrict__ xres,
    const float* __restrict__ gate)
{
  __shared__ u16 sA[128*64];
  __shared__ u16 sB[128*64];
  const int tid = threadIdx.x;
  const int lane = tid & 63;
  const int wv = tid >> 6;
  const int quad = lane >> 4;
  const int l16 = lane & 15;
  const int rw = (wv >> 1) * 64;
  const int cw = (wv & 1) * 64;
  const int m0 = blockIdx.x * 128;   // m fastest for B-tile L2 reuse
  const int n0 = blockIdx.y * 128;

  f32x4 acc[4][4];
  #pragma unroll
  for (int i=0;i<4;i++){
    #pragma unroll
    for (int j=0;j<4;j++) acc[i][j] = zero4();
  }

  for (int kb = 0; kb < K; kb += 64){
    #pragma unroll
    for (int i=0;i<4;i++){
      int c = i*256 + tid, r = c >> 3, s = c & 7, g = s ^ (r & 7);
      gl_lds16(A + (size_t)(m0 + r)*lda + kb + g*8, &sA[c*8]);
    }
    #pragma unroll
    for (int i=0;i<4;i++){
      int c = i*256 + tid, r = c >> 3, s = c & 7, g = s ^ (r & 7);
      gl_lds16(B + (size_t)(n0 + r)*ldb + kb + g*8, &sB[c*8]);
    }
    __syncthreads();
    #pragma unroll
    for (int kc=0; kc<2; kc++){
      bf16x8 af[4], bfr[4];
      #pragma unroll
      for (int mt=0; mt<4; mt++){
        int row = rw + mt*16 + l16;
        int s = (kc*4 + quad) ^ (row & 7);
        af[mt] = *(const bf16x8*)&sA[row*64 + s*8];
      }
      #pragma unroll
      for (int nt=0; nt<4; nt++){
        int row = cw + nt*16 + l16;
        int s = (kc*4 + quad) ^ (row & 7);
        bfr[nt] = *(const bf16x8*)&sB[row*64 + s*8];
      }
      #pragma unroll
      for (int mt=0; mt<4; mt++){
        #pragma unroll
        for (int nt=0; nt<4; nt++)
          acc[mt][nt] = __builtin_amdgcn_mfma_f32_16x16x32_bf16(af[mt], bfr[nt], acc[mt][nt], 0, 0, 0);
      }
    }
    __syncthreads();
  }

  #pragma unroll
  for (int mt=0; mt<4; mt++){
    #pragma unroll
    for (int nt=0; nt<4; nt++){
      #pragma unroll
      for (int r=0;r<4;r++){
        int row = m0 + rw + mt*16 + quad*4 + r;
        int col = n0 + cw + nt*16 + l16;
        float v = acc[mt][nt][r];
        if (MODE==0){
          v += bias[col];
          ((u16*)C)[(size_t)row*ldc + col] = f2bf(v);
        } else {
          v += xres[(size_t)row*ldadd + col];
          ((u16*)C)[(size_t)row*ldc + col] = f2bf(v);
        }
      }
    }
  }
}

// ---------------- 256x256 8-phase pipelined GEMM (T1+T2+T3+T4+T5) ----------------
// C[m,n] = sum_k A[m,k]*B[n,k] + bias[n]. K % 64 == 0, M % 256 == 0, N % 256 == 0.
// 8 waves (2M x 4N), per-wave C = 128x64. BK=64, LDS double-buffered (128 KiB).

#define CFENCE asm volatile("" ::: "memory")
#define VMCNT(n) asm volatile("s_waitcnt vmcnt(" #n ")" ::: "memory")

// stage 64 contiguous rows [rb, rb+64) of a 256x64 tile: 512 threads x 16B
__device__ __forceinline__ void stA64(const u16* __restrict__ g, u16* __restrict__ lds,
                                      int rb, int kb, int lda, int tid){
  int ri = tid >> 3, s = tid & 7;
  int R = rb + ri;                    // rb % 8 == 0 -> R&7 == ri&7
  gl_lds16(g + (size_t)R*lda + kb + ((s ^ (R & 7)) << 3), &lds[(R << 6) + (s << 3)]);
}
// stage two 32-row stripes [rb,rb+32) and [rb+64,rb+96): 512 threads x 16B
__device__ __forceinline__ void stB32x2(const u16* __restrict__ g, u16* __restrict__ lds,
                                        int rb, int kb, int ldb, int tid){
  int ri = tid >> 3, s = tid & 7;
  int R = rb + (ri & 31) + ((ri >> 5) << 6);
  gl_lds16(g + (size_t)R*ldb + kb + ((s ^ (R & 7)) << 3), &lds[(R << 6) + (s << 3)]);
}

#define LDA_Q(QM) \
  _Pragma("unroll") \
  for (int mt=0; mt<4; ++mt){ \
    int row = wm*128 + ((QM)*4+mt)*16 + l16; \
    _Pragma("unroll") \
    for (int kc=0; kc<2; ++kc){ \
      int s = (kc*4+quad) ^ (row & 7); \
      af[mt][kc] = *(const bf16x8*)&sAb[row*64 + s*8]; \
    } \
  }

#define LDB_Q(dst, QN) \
  _Pragma("unroll") \
  for (int nt=0; nt<2; ++nt){ \
    int row = wn*64 + ((QN)*2+nt)*16 + l16; \
    _Pragma("unroll") \
    for (int kc=0; kc<2; ++kc){ \
      int s = (kc*4+quad) ^ (row & 7); \
      dst[nt][kc] = *(const bf16x8*)&sBb[row*64 + s*8]; \
    } \
  }

#define PHASE_MFMA(bfX, QM, QN) \
  __builtin_amdgcn_s_setprio(1); \
  _Pragma("unroll") \
  for (int mt=0; mt<4; ++mt){ \
    _Pragma("unroll") \
    for (int kc=0; kc<2; ++kc){ \
      _Pragma("unroll") \
      for (int nt=0; nt<2; ++nt) \
        acc[(QM)*4+mt][(QN)*2+nt] = __builtin_amdgcn_mfma_f32_16x16x32_bf16( \
            af[mt][kc], bfX[nt][kc], acc[(QM)*4+mt][(QN)*2+nt], 0, 0, 0); \
    } \
  } \
  __builtin_amdgcn_s_setprio(0);

// the shared 8-phase K-loop (operates on Ab/Bb already offset to this block's
// m/n/k origin; NT K-tiles of 64)
#define GEMM256_BODY \
  f32x4 acc[8][4]; \
  _Pragma("unroll") \
  for (int i=0;i<8;i++){ \
    _Pragma("unroll") \
    for (int j=0;j<4;j++) acc[i][j] = zero4(); \
  } \
  stA64 (Ab, sA[0],   0, 0, lda, tid);  stA64 (Ab, sA[0], 128, 0, lda, tid); \
  stB32x2(Bb, sB[0],  0, 0, ldb, tid);  stB32x2(Bb, sB[0], 128, 0, ldb, tid); \
  stA64 (Ab, sA[0],  64, 0, lda, tid);  stA64 (Ab, sA[0], 192, 0, lda, tid); \
  stB32x2(Bb, sB[0], 32, 0, ldb, tid);  stB32x2(Bb, sB[0], 160, 0, ldb, tid); \
  if (NT > 1){ \
    stA64 (Ab, sA[1],   0, 64, lda, tid);  stA64 (Ab, sA[1], 128, 64, lda, tid); \
    stB32x2(Bb, sB[1],  0, 64, ldb, tid);  stB32x2(Bb, sB[1], 128, 64, ldb, tid); \
  } \
  VMCNT(4); \
  CFENCE; __builtin_amdgcn_s_barrier(); CFENCE; \
  bf16x8 af[4][2], bf0[2][2], bf1[2][2]; \
  for (int t = 0; t < NT; ++t){ \
    const int buf = t & 1; \
    const u16* sAb = sA[buf]; \
    const u16* sBb = sB[buf]; \
    u16* sAc = sA[buf]; \
    u16* sBc = sB[buf]; \
    u16* sAn = sA[buf ^ 1]; \
    u16* sBn = sB[buf ^ 1]; \
    const int kb1 = (t+1) << 6; \
    const int kb2 = (t+2) << 6; \
    const bool p1 = (t+1 < NT); \
    const bool p2 = (t+2 < NT); \
    LDA_Q(0) \
    LDB_Q(bf0, 0) \
    if (p1){ stA64(Ab, sAn, 64, kb1, lda, tid); stA64(Ab, sAn, 192, kb1, lda, tid); } \
    CFENCE; __builtin_amdgcn_s_barrier(); CFENCE; \
    PHASE_MFMA(bf0, 0, 0) \
    if (p1){ VMCNT(6); } else { VMCNT(0); } \
    CFENCE; __builtin_amdgcn_s_barrier(); CFENCE; \
    LDB_Q(bf1, 1) \
    if (p1){ stB32x2(Bb, sBn, 32, kb1, ldb, tid); stB32x2(Bb, sBn, 160, kb1, ldb, tid); } \
    CFENCE; __builtin_amdgcn_s_barrier(); CFENCE; \
    PHASE_MFMA(bf1, 0, 1) \
    CFENCE; __builtin_amdgcn_s_barrier(); CFENCE; \
    LDA_Q(1) \
    if (p2){ stA64(Ab, sAc, 0, kb2, lda, tid); stA64(Ab, sAc, 128, kb2, lda, tid); } \
    CFENCE; __builtin_amdgcn_s_barrier(); CFENCE; \
    PHASE_MFMA(bf0, 1, 0) \
    CFENCE; __builtin_amdgcn_s_barrier(); CFENCE; \
    if (p2){ stB32x2(Bb, sBc, 0, kb2, ldb, tid); stB32x2(Bb, sBc, 128, kb2, ldb, tid); } \
    CFENCE; __builtin_amdgcn_s_barrier(); CFENCE; \
    PHASE_MFMA(bf1, 1, 1) \
    if (p2){ VMCNT(8); } else if (p1){ VMCNT(4); } else { VMCNT(0); } \
    CFENCE; __builtin_amdgcn_s_barrier(); CFENCE; \
  }

// flat grid 672 = 8 XCDs x 84; bijective swizzle: XCD k gets nid [84k,84k+84),
// m fastest -> 8 concurrent same-XCD blocks share one B-panel (L2-resident).
// Tail columns (n0>=9216) apply gelu and write to cat directly (hbuf tail is
// never materialized; it was only ever consumed by the old gelu kernel).
__global__ void __launch_bounds__(512, 2) gemm256_bias(
    const u16* __restrict__ A, const u16* __restrict__ B, u16* __restrict__ C,
    int K, int lda, int ldb, int ldc, const float* __restrict__ bias,
    u16* __restrict__ cat)
{
  __shared__ u16 sA[2][256*64];
  __shared__ u16 sB[2][256*64];
  const int tid  = threadIdx.x;
  const int lane = tid & 63;
  const int wv   = tid >> 6;
  const int quad = lane >> 4;
  const int l16  = lane & 15;
  const int wm   = wv >> 2;          // 0..1
  const int wn   = wv & 3;           // 0..3
  const int lin  = blockIdx.x;       // 0..671
  const int nid  = (lin & 7)*84 + (lin >> 3);
  const int m0   = (nid & 7) * 256;
  const int n0   = (nid >> 3) * 256;
  const u16* Ab  = A + (size_t)m0 * lda;
  const u16* Bb  = B + (size_t)n0 * ldb;
  const int NT   = K >> 6;

  GEMM256_BODY

  if (n0 >= 9216){
    // epilogue: gelu -> cat (cols 3072 + (col-9216))
    #pragma unroll
    for (int mt=0; mt<8; ++mt){
      #pragma unroll
      for (int nt=0; nt<4; ++nt){
        #pragma unroll
        for (int r=0;r<4;++r){
          int row = m0 + wm*128 + mt*16 + quad*4 + r;
          int col = n0 + wn*64 + nt*16 + l16;
          float v = acc[mt][nt][r] + bias[col];
          float u = 0.7978845608028654f * (v + 0.044715f*v*v*v);
          float t = 1.f - 2.f/(__expf(2.f*u) + 1.f);   // tanh(u)
          cat[(size_t)row*CATK + 3072 + (col - 9216)] = f2bf(0.5f*v*(1.f + t));
        }
      }
    }
  } else {
    // epilogue: bf16 store + bias
    #pragma unroll
    for (int mt=0; mt<8; ++mt){
      #pragma unroll
      for (int nt=0; nt<4; ++nt){
        #pragma unroll
        for (int r=0;r<4;++r){
          int row = m0 + wm*128 + mt*16 + quad*4 + r;
          int col = n0 + wn*64 + nt*16 + l16;
          float v = acc[mt][nt][r] + bias[col];
          C[(size_t)row*ldc + col] = f2bf(v);
        }
      }
    }
  }
}

// split-K variant, flat grid 768 = 8 XCDs x 96: z = lin&7 (each XCD owns one
// K-chunk -> its ~20 MB operand chunk streams through its own L2). Each split
// writes its own bf16 partial buffer NON-atomically (no RMW, no zero-fill);
// final_epilogue sums the 8 partials.
__global__ void __launch_bounds__(512, 2) gemm256_splitk(
    const u16* __restrict__ A, const u16* __restrict__ B, u16* __restrict__ SP,
    int KS, int lda, int ldb, int ldc)
{
  __shared__ u16 sA[2][256*64];
  __shared__ u16 sB[2][256*64];
  const int tid  = threadIdx.x;
  const int lane = tid & 63;
  const int wv   = tid >> 6;
  const int quad = lane >> 4;
  const int l16  = lane & 15;
  const int wm   = wv >> 2;          // 0..1
  const int wn   = wv & 3;           // 0..3
  const int lin  = blockIdx.x;       // 0..767
  const int z    = lin & 7;
  int idx = (lin >> 3) + z*12;
  idx = (idx >= 96) ? idx - 96 : idx;   // bijective
  const int m0   = (idx & 7) * 256;
  const int n0   = (idx >> 3) * 256;
  const int kbase = z * KS;
  const u16* Ab  = A + (size_t)m0 * lda + kbase;
  const u16* Bb  = B + (size_t)n0 * ldb + kbase;
  const int NT   = KS >> 6;

  GEMM256_BODY

  // epilogue: plain bf16 partial store
  u16* Sp = SP + (size_t)z * SPN;
  #pragma unroll
  for (int mt=0; mt<8; ++mt){
    #pragma unroll
    for (int nt=0; nt<4; ++nt){
      #pragma unroll
      for (int r=0;r<4;++r){
        int row = m0 + wm*128 + mt*16 + quad*4 + r;
        int col = n0 + wn*64 + nt*16 + l16;
        Sp[(size_t)row*ldc + col] = f2bf(acc[mt][nt][r]);
      }
    }
  }
}

#undef LDA_Q
#undef LDB_Q
#undef PHASE_MFMA
#undef GEMM256_BODY

// ---------------- flash attention: one block = (head, 64 q-rows) ----------------
// flat grid 768 = 8 XCDs x 96: XCD k serves heads [3k,3k+3) -> per-head K/V
// becomes L2-resident on exactly one XCD.
// V staging: in-register 4xd transpose from coalesced u64 loads, 4x ds_write_b128
// per thread with swizzle s = kv8 ^ (d&7) ^ ((d>>3)&7).
__global__ void __launch_bounds__(256) attn_kernel(
    const u16* __restrict__ qbf, const u16* __restrict__ kbf,
    const u16* __restrict__ h, u16* __restrict__ cat)
{
  __shared__ u16 sQ[64*128];
  __shared__ u16 sK[64*128];
  __shared__ u16 sVT[128*64];
  __shared__ u16 sP[4*16*64];

  const int tid = threadIdx.x;
  const int lane = tid & 63;
  const int wv = tid >> 6;
  const int quad = lane >> 4;
  const int l16 = lane & 15;
  const int lin = blockIdx.x;          // 0..767
  const int nid = (lin & 7)*96 + (lin >> 3);
  const int l0 = (nid & 31) * 64;
  const int hh = nid >> 5;

  const u16* qb = qbf + (size_t)hh*SEQ*128;
  const u16* kbp = kbf + (size_t)hh*SEQ*128;

  #pragma unroll
  for (int i=0;i<4;i++){
    int c = i*256 + tid, r = c >> 4, s = c & 15, g = s ^ (r & 15);
    gl_lds16(qb + (size_t)(l0 + r)*128 + g*8, &sQ[c*8]);
  }

  // per-thread V staging geometry (constant across tiles)
  const int kv8 = tid >> 5;            // 0..7 (kv group of 8 rows)
  const int d4  = (tid & 31) * 4;      // 0..124 (4 consecutive d)

  f32x4 accO[8];
  #pragma unroll
  for (int i=0;i<8;i++) accO[i] = zero4();
  float m_i[4] = {-INFINITY,-INFINITY,-INFINITY,-INFINITY};
  float l_i[4] = {0.f,0.f,0.f,0.f};

  for (int kv0 = 0; kv0 < SEQ; kv0 += 64){
    #pragma unroll
    for (int i=0;i<4;i++){
      int c = i*256 + tid, r = c >> 4, s = c & 15, g = s ^ (r & 15);
      gl_lds16(kbp + (size_t)(kv0 + r)*128 + g*8, &sK[c*8]);
    }
    // stage V transposed: 8 coalesced u64 loads (8 kv rows x 4 d), in-register
    // transpose, 4x ds_write_b128
    {
      const u16* src = h + (size_t)(kv0 + kv8*8)*N1 + 6144 + (size_t)hh*128 + d4;
      u64 vv[8];
      #pragma unroll
      for (int j=0;j<8;j++) vv[j] = *(const u64*)(src + (size_t)j*N1);
      #pragma unroll
      for (int jd=0;jd<4;jd++){
        int d = d4 + jd;
        union { u16 u[8]; uint4 q; } t;
        #pragma unroll
        for (int j=0;j<8;j++) t.u[j] = (u16)(vv[j] >> (16*jd));
        int s = kv8 ^ (d & 7) ^ ((d >> 3) & 7);
        *(uint4*)&sVT[d*64 + s*8] = t.q;
      }
    }
    __syncthreads();

    // S = Q K^T (this wave's 16 q-rows x 64 kv)
    f32x4 sacc[4];
    #pragma unroll
    for (int i=0;i<4;i++) sacc[i] = zero4();
    __builtin_amdgcn_s_setprio(1);
    #pragma unroll
    for (int kc=0; kc<4; kc++){
      int arow = wv*16 + l16;
      int as = (kc*4 + quad) ^ (arow & 15);
      bf16x8 aF = *(const bf16x8*)&sQ[arow*128 + as*8];
      #pragma unroll
      for (int nt=0; nt<4; nt++){
        int brow = nt*16 + l16;
        int bs = (kc*4 + quad) ^ (brow & 15);
        bf16x8 bF = *(const bf16x8*)&sK[brow*128 + bs*8];
        sacc[nt] = __builtin_amdgcn_mfma_f32_16x16x32_bf16(aF, bF, sacc[nt], 0, 0, 0);
      }
    }
    __builtin_amdgcn_s_setprio(0);
    const float scl = 0.08838834764831845f;  // 1/sqrt(128)
    #pragma unroll
    for (int nt=0; nt<4; nt++){
      #pragma unroll
      for (int r=0;r<4;r++) sacc[nt][r] *= scl;
    }

    // in-register online softmax (rows live in the 16 lanes of a quad)
    float alpha[4];
    #pragma unroll
    for (int r=0;r<4;r++){
      float v = fmaxf(fmaxf(sacc[0][r],sacc[1][r]), fmaxf(sacc[2][r],sacc[3][r]));
      v = fmaxf(v, __shfl_xor(v,1,64));
      v = fmaxf(v, __shfl_xor(v,2,64));
      v = fmaxf(v, __shfl_xor(v,4,64));
      v = fmaxf(v, __shfl_xor(v,8,64));
      float mnew = fmaxf(m_i[r], v);
      alpha[r] = __expf(m_i[r] - mnew);
      m_i[r] = mnew;
    }
    float p[4][4];
    float rsum[4] = {0.f,0.f,0.f,0.f};
    #pragma unroll
    for (int nt=0; nt<4; nt++){
      #pragma unroll
      for (int r=0;r<4;r++){
        float pv = __expf(sacc[nt][r] - m_i[r]);
        p[nt][r] = pv;
        rsum[r] += pv;
      }
    }
    #pragma unroll
    for (int r=0;r<4;r++){
      float s = rsum[r];
      s += __shfl_xor(s,1,64); s += __shfl_xor(s,2,64);
      s += __shfl_xor(s,4,64); s += __shfl_xor(s,8,64);
      l_i[r] = l_i[r]*alpha[r] + s;
    }
    // write P (C-layout -> A-layout via LDS, per-wave region)
    u16* pw = &sP[wv*1024];
    #pragma unroll
    for (int nt=0; nt<4; nt++){
      #pragma unroll
      for (int r=0;r<4;r++){
        int rloc = quad*4 + r;
        int c = nt*16 + l16;
        int slot = (c >> 3) ^ (rloc & 7);
        pw[rloc*64 + slot*8 + (c & 7)] = f2bf(p[nt][r]);
      }
    }
    // rescale O
    #pragma unroll
    for (int dt=0; dt<8; dt++){
      #pragma unroll
      for (int r=0;r<4;r++) accO[dt][r] *= alpha[r];
    }
    // O += P V
    int prow = l16;
    int ps0 = quad ^ (prow & 7);
    int ps1 = (4 + quad) ^ (prow & 7);
    bf16x8 p0 = *(const bf16x8*)&pw[prow*64 + ps0*8];
    bf16x8 p1 = *(const bf16x8*)&pw[prow*64 + ps1*8];
    __builtin_amdgcn_s_setprio(1);
    #pragma unroll
    for (int dt=0; dt<8; dt++){
      int vrow = dt*16 + l16;
      int hs = (vrow >> 3) & 7;
      int vs0 = (quad ^ (vrow & 7) ^ hs);
      int vs1 = ((4 + quad) ^ (vrow & 7) ^ hs);
      bf16x8 v0 = *(const bf16x8*)&sVT[vrow*64 + vs0*8];
      bf16x8 v1 = *(const bf16x8*)&sVT[vrow*64 + vs1*8];
      accO[dt] = __builtin_amdgcn_mfma_f32_16x16x32_bf16(p0, v0, accO[dt], 0, 0, 0);
      accO[dt] = __builtin_amdgcn_mfma_f32_16x16x32_bf16(p1, v1, accO[dt], 0, 0, 0);
    }
    __builtin_amdgcn_s_setprio(0);
    __syncthreads();
  }

  #pragma unroll
  for (int dt=0; dt<8; dt++){
    #pragma unroll
    for (int r=0;r<4;r++){
      int row = l0 + wv*16 + quad*4 + r;
      int col = hh*128 + dt*16 + l16;
      cat[(size_t)row*CATK + col] = f2bf(accO[dt][r] / l_i[r]);
    }
  }
}

// ---------------- launcher ----------------
extern "C" void kernel_launch(void* const* d_in, const int* in_sizes, int n_in,
                              void* d_out, int out_size, void* d_ws, size_t ws_size,
                              hipStream_t stream)
{
  (void)in_sizes; (void)n_in; (void)out_size; (void)ws_size;
  const float* x    = (const float*)d_in[0];
  const float* vec  = (const float*)d_in[1];
  const float* pe   = (const float*)d_in[2];
  const float* modw = (const float*)d_in[3];
  const float* modb = (const float*)d_in[4];
  const float* w1   = (const float*)d_in[5];
  const float* b1   = (const float*)d_in[6];
  const float* w2   = (const float*)d_in[7];
  const float* b2   = (const float*)d_in[8];
  const float* qs   = (const float*)d_in[9];
  const float* ks   = (const float*)d_in[10];
  const float* lqd  = (const float*)d_in[11];
  const float* lqu  = (const float*)d_in[12];
  const float* lkd  = (const float*)d_in[13];
  const float* lku  = (const float*)d_in[14];
  const float* lvd  = (const float*)d_in[15];
  const float* lvu  = (const float*)d_in[16];
  const float* pd   = (const float*)d_in[17];
  const float* pu   = (const float*)d_in[18];
  float* out = (float*)d_out;

  char* ws = (char*)d_ws;
  float* mvec  = (float*)(ws + 12288);        // 9216 f32 (gate = mvec+6144, live to end)
  u16* xm      = (u16*)(ws + 49152);          // 2048 x 3072  (dead after gemm256_bias)
  u16* Spart   = (u16*)(ws + 49152);          // 8 x 2048 x 3072 bf16 partials (overlays xm/U/DT/pubf/pdT,
                                              //  ends at 49152+100663296 < w2ext offset)
  u16* U       = (u16*)(ws + 12632064);       // 9216 x 128
  u16* DT      = (u16*)(ws + 14991360);       // 3072 x 128
  u16* pubf    = (u16*)(ws + 15777792);       // 3072 x 64
  u16* pdT     = (u16*)(ws + 16171008);       // 15360 x 64
  u16* w1ext   = (u16*)(ws + 18137088);       // 21504 x 3072 (dead after gemm256_bias)
  u16* w2ext   = (u16*)(ws + 150257664);      // 3072 x 15360
  u16* hbuf    = (u16*)(ws + 244629504);      // 2048 x 21504 (only cols < 9216 written now)
  u16* qbf     = (u16*)(ws + 332709888);      // 24 x 2048 x 128
  u16* kbf     = (u16*)(ws + 345292800);      // 24 x 2048 x 128
  u16* cat     = (u16*)(ws + 357875712);      // 2048 x 15360

  // weight prep (lora folded: w1' = w1 + U@Dcat, w2' = w2 + pu@pd)
  cast_w1_tail<<<18432,256,0,stream>>>(w1, w1ext);
  build_ustack<<<576,256,0,stream>>>(lqu,lku,lvu,U);
  build_dcatT<<<192,256,0,stream>>>(lqd,lkd,lvd,DT);
  build_pubf<<<96,256,0,stream>>>(pu,pubf);
  build_pdT<<<480,256,0,stream>>>(pd,pdT);
  // w1ext[0:9216] = bf16(U @ DT^T + w1)     M=9216 N=3072 K=128
  gemm_bt<3><<<dim3(72,24),256,0,stream>>>(U,DT,(void*)w1ext,
      128,128,128,K1,K1,nullptr,w1,nullptr);
  // w2ext = bf16(pubf @ pdT^T + w2)         M=3072 N=15360 K=64
  gemm_bt<3><<<dim3(24,120),256,0,stream>>>(pubf,pdT,(void*)w2ext,
      64,64,64,CATK,CATK,nullptr,w2,nullptr);

  // activations
  modgemv_kernel<<<9216,256,0,stream>>>(vec,modw,modb,mvec);   // silu fused
  xmod_kernel<<<2048,256,0,stream>>>(x,mvec,xm);
  // h = x_mod @ w1ext^T + b1   (tail cols gelu->cat fused)    M=2048 N=21504 K=3072
  gemm256_bias<<<672,512,0,stream>>>(xm,w1ext,hbuf,K1,K1,K1,N1,b1,cat);
  qkv_kernel<<<dim3(2048,24),128,0,stream>>>(hbuf,pe,qs,ks,qbf,kbf);
  attn_kernel<<<768,256,0,stream>>>(qbf,kbf,hbuf,cat);
  // Spart[z] = cat @ w2ext[:, zK:(z+1)K]^T  (split-K=8, one K-chunk per XCD, no atomics)
  gemm256_splitk<<<768,512,0,stream>>>(cat,w2ext,Spart,
      CATK/8,CATK,CATK,3072);
  // out = x + gate*(sum_z Spart[z] + b2)
  final_epilogue<<<dim3(2048,3),256,0,stream>>>(Spart,x,mvec+6144,b2,out);
}